// Round 2
// baseline (5679.734 us; speedup 1.0000x reference)
//
#include <hip/hip_runtime.h>
#include <math.h>

// ---------------------------------------------------------------------------
// DetModel: two fused 3-conv branches + tiny classifier.
// Classifier runs FIRST (depends only on f4); conv3 computes ONLY the
// cls-selected channels -> offsets_full/weights_full never materialized.
// R1 fix: SAME-padding semantics — h1/h2 must be ZERO outside the image;
// halo recompute leaked nonzero values at border tiles. Mask on LDS write.
// ---------------------------------------------------------------------------

// ---------------- classifier: gap -> 256x128 -> 128x128 -> 128x3 -----------
__global__ void cls_kernel(const float* __restrict__ f4,
                           const float* __restrict__ Wc1, const float* __restrict__ bc1,
                           const float* __restrict__ Wc2, const float* __restrict__ bc2,
                           const float* __restrict__ Wc3, const float* __restrict__ bc3,
                           float* __restrict__ pred_out, int* __restrict__ cls_out) {
    int b = blockIdx.x;
    int t = threadIdx.x;
    __shared__ float gap[256];
    __shared__ float z1[128];
    __shared__ float z2[128];
    __shared__ float lg[3];
    const float* f = f4 + (size_t)b * 1024 * 256;
    float s = 0.f;
    for (int p = 0; p < 1024; ++p) s += f[(size_t)p * 256 + t];
    gap[t] = s * (1.0f / 1024.0f);
    __syncthreads();
    if (t < 128) {
        float a = bc1[t];
        for (int i = 0; i < 256; ++i) a += gap[i] * Wc1[i * 128 + t];
        z1[t] = fmaxf(a, 0.f);
    }
    __syncthreads();
    if (t < 128) {
        float a = bc2[t];
        for (int i = 0; i < 128; ++i) a += z1[i] * Wc2[i * 128 + t];
        z2[t] = fmaxf(a, 0.f);
    }
    __syncthreads();
    if (t < 3) {
        float a = bc3[t];
        for (int i = 0; i < 128; ++i) a += z2[i] * Wc3[i * 3 + t];
        lg[t] = a;
    }
    __syncthreads();
    if (t == 0) {
        float m = fmaxf(lg[0], fmaxf(lg[1], lg[2]));
        float e0 = expf(lg[0] - m), e1 = expf(lg[1] - m), e2 = expf(lg[2] - m);
        float ssum = e0 + e1 + e2;
        pred_out[b * 3 + 0] = e0 / ssum;
        pred_out[b * 3 + 1] = e1 / ssum;
        pred_out[b * 3 + 2] = e2 / ssum;
        int idx = 0; float best = lg[0];
        if (lg[1] > best) { best = lg[1]; idx = 1; }
        if (lg[2] > best) { best = lg[2]; idx = 2; }
        cls_out[b] = idx;
    }
}

// ---------------- fused conv branch ----------------------------------------
// 8x8 output tile per block. Regions: x0 14x14, h1 12x12, h2 10x10.
// LDS layout (words):
//   [0, 1568)        x0 chunk [14][14][8]          (stage 1)
//   [1568, 6176)     weight chunk [9][8][64]       (stages 1,2)
//   [6176, 15968)    h1 [144][68]  (row pad 68)
//   [0, 6400)        h2 [64][100]  (stage 3; overlaps dead x0/w regions)
//   [6400, 6656)     reduce buffer (stage 3; overlaps dead h1 head)
#define X0_OFF 0
#define W_OFF  1568
#define H1_OFF 6176
#define H1PAD  68
#define H2_OFF 0
#define RED_OFF 6400
#define LDS_WORDS 15968

__global__ __launch_bounds__(256, 2)
void fused_branch(const float* __restrict__ x0,
                  const float* __restrict__ W1, const float* __restrict__ B1,
                  const float* __restrict__ W2, const float* __restrict__ B2,
                  const float* __restrict__ W3, const float* __restrict__ B3,
                  const int* __restrict__ clsp,
                  float* __restrict__ outp, int NCH, int C3TOT) {
    __shared__ float sh[LDS_WORDS];
    const int t = threadIdx.x;
    const int b = blockIdx.y;
    const int ty0 = (blockIdx.x >> 6) * 8;
    const int tx0 = (blockIdx.x & 63) * 8;
    const int cg = t & 15, pg = t >> 4;
    const int c4 = cg * 4;

    // ================= stage 1: h1 = relu(conv(x0, W1)+B1), 12x12x64 =======
    float4 acc1[9];
#pragma unroll
    for (int k = 0; k < 9; ++k) acc1[k] = make_float4(0.f, 0.f, 0.f, 0.f);
    int xbase[9];
#pragma unroll
    for (int k = 0; k < 9; ++k) {
        int p = pg + 16 * k;              // 0..143
        int py = p / 12, px = p - py * 12;
        xbase[k] = (py * 14 + px) * 8;
    }

    for (int ci0 = 0; ci0 < 32; ci0 += 8) {
        // load x0 chunk 14x14x8 (392 float4), zero-padded at image border
#pragma unroll
        for (int it = 0; it < 2; ++it) {
            int v = t + it * 256;
            if (v < 392) {
                int ly = v / 28; int rem = v - ly * 28;
                int lx = rem >> 1; int lc4 = rem & 1;
                int gy = ty0 - 3 + ly, gx = tx0 - 3 + lx;
                float4 val = make_float4(0.f, 0.f, 0.f, 0.f);
                if ((unsigned)gy < 512u && (unsigned)gx < 512u)
                    val = *(const float4*)&x0[((((size_t)b * 512 + gy) * 512 + gx) * 32) + ci0 + lc4 * 4];
                *(float4*)&sh[X0_OFF + (ly * 14 + lx) * 8 + lc4 * 4] = val;
            }
        }
        // load W1 chunk [9][8][64] (1152 float4)
#pragma unroll
        for (int it = 0; it < 5; ++it) {
            int v = t + it * 256;
            if (v < 1152) {
                int co4 = v & 15; int rest = v >> 4;   // rest = dxy*8 + lc
                int lc = rest & 7; int dxy = rest >> 3;
                float4 w = *(const float4*)&W1[((size_t)(dxy * 32 + ci0 + lc)) * 64 + co4 * 4];
                *(float4*)&sh[W_OFF + (dxy * 8 + lc) * 64 + co4 * 4] = w;
            }
        }
        __syncthreads();
        for (int dy = 0; dy < 3; ++dy)
            for (int dx = 0; dx < 3; ++dx) {
                int rowoff = (dy * 14 + dx) * 8;
                int wrow = ((dy * 3 + dx) * 8) * 64;
#pragma unroll
                for (int ci = 0; ci < 8; ++ci) {
                    float4 w = *(const float4*)&sh[W_OFF + wrow + ci * 64 + c4];
                    int off = X0_OFF + rowoff + ci;
#pragma unroll
                    for (int k = 0; k < 9; ++k) {
                        float x = sh[off + xbase[k]];
                        acc1[k].x += x * w.x; acc1[k].y += x * w.y;
                        acc1[k].z += x * w.z; acc1[k].w += x * w.w;
                    }
                }
            }
        __syncthreads();
    }
    {
        float4 bb = *(const float4*)&B1[c4];
#pragma unroll
        for (int k = 0; k < 9; ++k) {
            int p = pg + 16 * k;
            int py = p / 12, px = p - py * 12;
            // SAME-padding: h1 is zero outside the image
            int gy = ty0 - 2 + py, gx = tx0 - 2 + px;
            bool valid = ((unsigned)gy < 512u) && ((unsigned)gx < 512u);
            float4 v;
            v.x = valid ? fmaxf(acc1[k].x + bb.x, 0.f) : 0.f;
            v.y = valid ? fmaxf(acc1[k].y + bb.y, 0.f) : 0.f;
            v.z = valid ? fmaxf(acc1[k].z + bb.z, 0.f) : 0.f;
            v.w = valid ? fmaxf(acc1[k].w + bb.w, 0.f) : 0.f;
            *(float4*)&sh[H1_OFF + p * H1PAD + c4] = v;
        }
    }
    __syncthreads();

    // ================= stage 2: h2 = relu(conv(h1, W2)+B2), 10x10x64 =======
    float4 acc2[7];
#pragma unroll
    for (int k = 0; k < 7; ++k) acc2[k] = make_float4(0.f, 0.f, 0.f, 0.f);
    int hbase[7];
#pragma unroll
    for (int k = 0; k < 7; ++k) {
        int p = pg + 16 * k;
        int pv = p < 100 ? p : 99;        // clamp for safe (unused) address
        int py = pv / 10, px = pv - py * 10;
        hbase[k] = (py * 12 + px) * H1PAD;
    }

    for (int ci0 = 0; ci0 < 64; ci0 += 8) {
#pragma unroll
        for (int it = 0; it < 5; ++it) {
            int v = t + it * 256;
            if (v < 1152) {
                int co4 = v & 15; int rest = v >> 4;
                int lc = rest & 7; int dxy = rest >> 3;
                float4 w = *(const float4*)&W2[((size_t)(dxy * 64 + ci0 + lc)) * 64 + co4 * 4];
                *(float4*)&sh[W_OFF + (dxy * 8 + lc) * 64 + co4 * 4] = w;
            }
        }
        __syncthreads();
        for (int dy = 0; dy < 3; ++dy)
            for (int dx = 0; dx < 3; ++dx) {
                int rowoff = (dy * 12 + dx) * H1PAD + ci0;
                int wrow = ((dy * 3 + dx) * 8) * 64;
#pragma unroll
                for (int ci = 0; ci < 8; ++ci) {
                    float4 w = *(const float4*)&sh[W_OFF + wrow + ci * 64 + c4];
                    int off = H1_OFF + rowoff + ci;
#pragma unroll
                    for (int k = 0; k < 7; ++k) {
                        float x = sh[off + hbase[k]];
                        acc2[k].x += x * w.x; acc2[k].y += x * w.y;
                        acc2[k].z += x * w.z; acc2[k].w += x * w.w;
                    }
                }
            }
        __syncthreads();
    }
    // write h2 as [ci][100] into LDS offset 0 (x0/w regions now dead)
    {
        float4 bb = *(const float4*)&B2[c4];
#pragma unroll
        for (int k = 0; k < 7; ++k) {
            int p = pg + 16 * k;
            if (p < 100) {
                int py = p / 10, px = p - py * 10;
                // SAME-padding: h2 is zero outside the image
                int gy = ty0 - 1 + py, gx = tx0 - 1 + px;
                bool valid = ((unsigned)gy < 512u) && ((unsigned)gx < 512u);
                sh[H2_OFF + (c4 + 0) * 100 + p] = valid ? fmaxf(acc2[k].x + bb.x, 0.f) : 0.f;
                sh[H2_OFF + (c4 + 1) * 100 + p] = valid ? fmaxf(acc2[k].y + bb.y, 0.f) : 0.f;
                sh[H2_OFF + (c4 + 2) * 100 + p] = valid ? fmaxf(acc2[k].z + bb.z, 0.f) : 0.f;
                sh[H2_OFF + (c4 + 3) * 100 + p] = valid ? fmaxf(acc2[k].w + bb.w, 0.f) : 0.f;
            }
        }
    }
    __syncthreads();

    // ================= stage 3: selected channels of conv(h2, W3)+B3 =======
    const int cls = clsp[b];
    const int pxl = t & 63;
    const int r = t >> 6;                       // 0..3
    const int ch = (NCH == 2) ? (r & 1) : 0;
    const int kp = (NCH == 2) ? (r >> 1) : r;   // K-split index
    const int KW = (NCH == 2) ? 32 : 16;
    const int ci0 = kp * KW;
    const int selc = cls * NCH + ch;
    const int py = pxl >> 3, px = pxl & 7;

    float a = 0.f;
    for (int dy = 0; dy < 3; ++dy)
        for (int dx = 0; dx < 3; ++dx) {
            int ppb = (py + dy) * 10 + (px + dx);
            const float* wp = &W3[(size_t)((dy * 3 + dx) * 64 + ci0) * C3TOT + selc];
            for (int ci = 0; ci < KW; ++ci)
                a += sh[H2_OFF + (ci0 + ci) * 100 + ppb] * wp[ci * C3TOT];
        }
    sh[RED_OFF + t] = a;
    __syncthreads();
    if (r < NCH) {
        float s = 0.f;
        int KS = 4 / NCH;
        for (int k2 = 0; k2 < KS; ++k2) s += sh[RED_OFF + (k2 * NCH + ch) * 64 + pxl];
        s += B3[selc];
        int gy = ty0 + py, gx = tx0 + px;
        outp[(((size_t)b * 512 + gy) * 512 + gx) * NCH + ch] = s;
    }
}

extern "C" void kernel_launch(void* const* d_in, const int* in_sizes, int n_in,
                              void* d_out, int out_size, void* d_ws, size_t ws_size,
                              hipStream_t stream) {
    const float* x0  = (const float*)d_in[0];
    const float* f4  = (const float*)d_in[1];
    const float* Wo1 = (const float*)d_in[2];  const float* bo1 = (const float*)d_in[3];
    const float* Wo2 = (const float*)d_in[4];  const float* bo2 = (const float*)d_in[5];
    const float* Wo3 = (const float*)d_in[6];  const float* bo3 = (const float*)d_in[7];
    const float* Ww1 = (const float*)d_in[8];  const float* bw1 = (const float*)d_in[9];
    const float* Ww2 = (const float*)d_in[10]; const float* bw2 = (const float*)d_in[11];
    const float* Ww3 = (const float*)d_in[12]; const float* bw3 = (const float*)d_in[13];
    const float* Wc1 = (const float*)d_in[14]; const float* bc1 = (const float*)d_in[15];
    const float* Wc2 = (const float*)d_in[16]; const float* bc2 = (const float*)d_in[17];
    const float* Wc3 = (const float*)d_in[18]; const float* bc3 = (const float*)d_in[19];

    float* out = (float*)d_out;
    float* offsets_out = out;                      // (4,512,512,2)
    float* weights_out = out + 2097152;            // (4,512,512,1)
    float* pred_out    = out + 3145728;            // (4,3)
    int* cls_ws = (int*)d_ws;

    cls_kernel<<<4, 256, 0, stream>>>(f4, Wc1, bc1, Wc2, bc2, Wc3, bc3, pred_out, cls_ws);

    dim3 grid(4096, 4);
    fused_branch<<<grid, 256, 0, stream>>>(x0, Wo1, bo1, Wo2, bo2, Wo3, bo3,
                                           cls_ws, offsets_out, 2, 6);
    fused_branch<<<grid, 256, 0, stream>>>(x0, Ww1, bw1, Ww2, bw2, Ww3, bw3,
                                           cls_ws, weights_out, 1, 3);
}

// Round 3
// 1249.040 us; speedup vs baseline: 4.5473x; 4.5473x over previous
//
#include <hip/hip_runtime.h>
#include <math.h>

typedef __attribute__((ext_vector_type(8))) short short8;
typedef __attribute__((ext_vector_type(4))) float floatx4;
typedef unsigned short ushort_t;
typedef unsigned int uint_t;

__device__ __forceinline__ ushort_t f2bf(float x) {   // RNE f32 -> bf16
    uint_t u = __float_as_uint(x);
    uint_t r = (u + 0x7fffu + ((u >> 16) & 1u)) >> 16;
    return (ushort_t)r;
}
__device__ __forceinline__ float bf2f(ushort_t h) {
    return __uint_as_float(((uint_t)h) << 16);
}

// ---------------- classifier: gap -> 256x128 -> 128x128 -> 128x3 -----------
__global__ void cls_kernel(const float* __restrict__ f4,
                           const float* __restrict__ Wc1, const float* __restrict__ bc1,
                           const float* __restrict__ Wc2, const float* __restrict__ bc2,
                           const float* __restrict__ Wc3, const float* __restrict__ bc3,
                           float* __restrict__ pred_out, int* __restrict__ cls_out) {
    int b = blockIdx.x;
    int t = threadIdx.x;                       // 1024 threads
    __shared__ float part[1024];
    __shared__ float gap[256];
    __shared__ float z1[128];
    __shared__ float z2[128];
    __shared__ float lg[3];
    const float* f = f4 + (size_t)b * 1024 * 256;
    int ci = t & 255, po = t >> 8;
    float s = 0.f;
    for (int p = po; p < 1024; p += 4) s += f[(size_t)p * 256 + ci];
    part[t] = s;
    __syncthreads();
    if (t < 256) gap[t] = (part[t] + part[t + 256] + part[t + 512] + part[t + 768]) * (1.0f / 1024.0f);
    __syncthreads();
    if (t < 128) {
        float a = bc1[t];
        for (int i = 0; i < 256; ++i) a += gap[i] * Wc1[i * 128 + t];
        z1[t] = fmaxf(a, 0.f);
    }
    __syncthreads();
    if (t < 128) {
        float a = bc2[t];
        for (int i = 0; i < 128; ++i) a += z1[i] * Wc2[i * 128 + t];
        z2[t] = fmaxf(a, 0.f);
    }
    __syncthreads();
    if (t < 3) {
        float a = bc3[t];
        for (int i = 0; i < 128; ++i) a += z2[i] * Wc3[i * 3 + t];
        lg[t] = a;
    }
    __syncthreads();
    if (t == 0) {
        float m = fmaxf(lg[0], fmaxf(lg[1], lg[2]));
        float e0 = expf(lg[0] - m), e1 = expf(lg[1] - m), e2 = expf(lg[2] - m);
        float ssum = e0 + e1 + e2;
        pred_out[b * 3 + 0] = e0 / ssum;
        pred_out[b * 3 + 1] = e1 / ssum;
        pred_out[b * 3 + 2] = e2 / ssum;
        int idx = 0; float best = lg[0];
        if (lg[1] > best) { best = lg[1]; idx = 1; }
        if (lg[2] > best) { best = lg[2]; idx = 2; }
        cls_out[b] = idx;
    }
}

// ---------------- fused MFMA conv branch -----------------------------------
// 12x12 out tile. x0 18x18 -> h1 16x16 -> h2 14x14 -> out (selected ch).
// LDS (ushort elems):
//   x0  [4 kslice][324 px][8]   : [0, 10368)
//   h1  [8 kslice][256 px][8]   : [10368, 26752)
//   W   chunk (per-tap)         : [26752, 30848)   (conv1 2048, conv2 4096)
//   h2  [196 px][72 pad]        : [0, 14112)   overwrites dead x0/h1-head
//   WSELf (float, 576*NCH)      : floats [13376, ...) == W region (post-conv2)
#define X0_E 0
#define H1_E 10368
#define W_E  26752
#define H2_E 0
#define WSEL_F 13376
#define LDS_E 30848

template<int NCH, int C3TOT>
__global__ __launch_bounds__(256, 2)
void fused_branch(const float* __restrict__ x0,
                  const float* __restrict__ W1, const float* __restrict__ B1,
                  const float* __restrict__ W2, const float* __restrict__ B2,
                  const float* __restrict__ W3, const float* __restrict__ B3,
                  const int* __restrict__ clsp,
                  float* __restrict__ outp) {
    __shared__ __align__(16) ushort_t lds[LDS_E];
    float* ldsf = (float*)lds;
    const int t = threadIdx.x;
    const int b = blockIdx.y;
    const int tileY = blockIdx.x / 43, tileX = blockIdx.x - tileY * 43;
    const int ty0 = tileY * 12, tx0 = tileX * 12;
    const int lane = t & 63, wave = t >> 6;
    const int m = lane & 15, q = lane >> 4;

    // ---- stage x0 (18x18x32 fp32 -> bf16 [4][324][8]) ----
    for (int idx = t; idx < 1296; idx += 256) {
        int pix = idx >> 2, qq = idx & 3;
        int py = pix / 18, px = pix - py * 18;
        int gy = ty0 - 3 + py, gx = tx0 - 3 + px;
        float4 v0 = {0, 0, 0, 0}, v1 = {0, 0, 0, 0};
        if ((uint_t)gy < 512u && (uint_t)gx < 512u) {
            const float* xp = x0 + (((size_t)b * 512 + gy) * 512 + gx) * 32 + qq * 8;
            v0 = *(const float4*)xp;
            v1 = *(const float4*)(xp + 4);
        }
        short8 pk;
        pk[0] = f2bf(v0.x); pk[1] = f2bf(v0.y); pk[2] = f2bf(v0.z); pk[3] = f2bf(v0.w);
        pk[4] = f2bf(v1.x); pk[5] = f2bf(v1.y); pk[6] = f2bf(v1.z); pk[7] = f2bf(v1.w);
        *(short8*)&lds[X0_E + (qq * 324 + pix) * 8] = pk;
    }
    __syncthreads();

    // ================= conv1: h1(16x16x64) via MFMA =================
    {
        floatx4 acc[4][4];
#pragma unroll
        for (int mi = 0; mi < 4; ++mi)
#pragma unroll
            for (int n = 0; n < 4; ++n) acc[mi][n] = (floatx4){0.f, 0.f, 0.f, 0.f};

        for (int dy = 0; dy < 3; ++dy)
        for (int dx = 0; dx < 3; ++dx) {
            int dydx = dy * 3 + dx;
            // stage W1 tap [64co][32ci] -> [4 kslice][64co][8]
            {
                int ci = t >> 3, co0 = (t & 7) * 8;
                const float* wp = W1 + (size_t)(dydx * 32 + ci) * 64 + co0;
                float4 w0 = *(const float4*)wp, w1 = *(const float4*)(wp + 4);
                ushort_t* d = &lds[W_E + (ci >> 3) * 512 + co0 * 8 + (ci & 7)];
                d[0 * 8] = f2bf(w0.x); d[1 * 8] = f2bf(w0.y);
                d[2 * 8] = f2bf(w0.z); d[3 * 8] = f2bf(w0.w);
                d[4 * 8] = f2bf(w1.x); d[5 * 8] = f2bf(w1.y);
                d[6 * 8] = f2bf(w1.z); d[7 * 8] = f2bf(w1.w);
            }
            __syncthreads();
            short8 Bf[4];
#pragma unroll
            for (int n = 0; n < 4; ++n)
                Bf[n] = *(const short8*)&lds[W_E + q * 512 + (n * 16 + m) * 8];
#pragma unroll
            for (int mi = 0; mi < 4; ++mi) {
                int Mt = wave + mi * 4;            // h1 row
                short8 A = *(const short8*)&lds[X0_E + q * 2592 + ((Mt + dy) * 18 + (m + dx)) * 8];
#pragma unroll
                for (int n = 0; n < 4; ++n)
                    acc[mi][n] = __builtin_amdgcn_mfma_f32_16x16x32_bf16(A, Bf[n], acc[mi][n], 0, 0, 0);
            }
            __syncthreads();
        }
        // epilogue: bias+relu+SAME-pad mask -> h1 [8][256][8]
#pragma unroll
        for (int n = 0; n < 4; ++n) {
            int co = n * 16 + m;
            float bias = B1[co];
            ushort_t* hb = &lds[H1_E + (co >> 3) * 2048 + (co & 7)];
#pragma unroll
            for (int mi = 0; mi < 4; ++mi) {
                int Mt = wave + mi * 4;
                int gy = ty0 - 2 + Mt;
#pragma unroll
                for (int r = 0; r < 4; ++r) {
                    int x = q * 4 + r;
                    int gx = tx0 - 2 + x;
                    bool ok = ((uint_t)gy < 512u) && ((uint_t)gx < 512u);
                    float v = fmaxf(acc[mi][n][r] + bias, 0.f);
                    hb[(Mt * 16 + x) * 8] = ok ? f2bf(v) : (ushort_t)0;
                }
            }
        }
    }
    __syncthreads();

    // ================= conv2: h2(14x14x64) via MFMA =================
    {
        floatx4 acc[4][4];
#pragma unroll
        for (int mi = 0; mi < 4; ++mi)
#pragma unroll
            for (int n = 0; n < 4; ++n) acc[mi][n] = (floatx4){0.f, 0.f, 0.f, 0.f};
        int hb2[4];
#pragma unroll
        for (int mi = 0; mi < 4; ++mi) {
            int p0 = (wave + mi * 4) * 16 + m;
            int py = p0 / 14, px = p0 - py * 14;
            hb2[mi] = py * 16 + px;
        }

        for (int dy = 0; dy < 3; ++dy)
        for (int dx = 0; dx < 3; ++dx) {
            int dydx = dy * 3 + dx;
            // stage W2 tap [64co][64ci] -> [8 kslice][64co][8]
            {
                int ci = t >> 2, co0 = (t & 3) * 16;
                const float* wp = W2 + (size_t)(dydx * 64 + ci) * 64 + co0;
                ushort_t* d = &lds[W_E + (ci >> 3) * 512 + co0 * 8 + (ci & 7)];
#pragma unroll
                for (int i4 = 0; i4 < 4; ++i4) {
                    float4 w = *(const float4*)(wp + i4 * 4);
                    d[(i4 * 4 + 0) * 8] = f2bf(w.x); d[(i4 * 4 + 1) * 8] = f2bf(w.y);
                    d[(i4 * 4 + 2) * 8] = f2bf(w.z); d[(i4 * 4 + 3) * 8] = f2bf(w.w);
                }
            }
            __syncthreads();
#pragma unroll
            for (int kh = 0; kh < 2; ++kh) {
                short8 Bf[4];
#pragma unroll
                for (int n = 0; n < 4; ++n)
                    Bf[n] = *(const short8*)&lds[W_E + (kh * 4 + q) * 512 + (n * 16 + m) * 8];
#pragma unroll
                for (int mi = 0; mi < 4; ++mi) {
                    int Mt = wave + mi * 4;
                    if (Mt < 13) {
                        short8 A = *(const short8*)&lds[H1_E + (kh * 4 + q) * 2048 + (hb2[mi] + dy * 16 + dx) * 8];
#pragma unroll
                        for (int n = 0; n < 4; ++n)
                            acc[mi][n] = __builtin_amdgcn_mfma_f32_16x16x32_bf16(A, Bf[n], acc[mi][n], 0, 0, 0);
                    }
                }
            }
            __syncthreads();
        }
        // epilogue: bias+relu+mask -> h2 [196][72] (overwrites dead x0/h1-head)
#pragma unroll
        for (int n = 0; n < 4; ++n) {
            int co = n * 16 + m;
            float bias = B2[co];
#pragma unroll
            for (int mi = 0; mi < 4; ++mi) {
                int Mt = wave + mi * 4;
                if (Mt >= 13) continue;
#pragma unroll
                for (int r = 0; r < 4; ++r) {
                    int pixel = Mt * 16 + q * 4 + r;
                    if (pixel < 196) {
                        int py = pixel / 14, px = pixel - py * 14;
                        int gy = ty0 - 1 + py, gx = tx0 - 1 + px;
                        bool ok = ((uint_t)gy < 512u) && ((uint_t)gx < 512u);
                        float v = fmaxf(acc[mi][n][r] + bias, 0.f);
                        lds[H2_E + pixel * 72 + co] = ok ? f2bf(v) : (ushort_t)0;
                    }
                }
            }
        }
    }

    // ---- stage selected W3 channels (W region is dead now) ----
    const int cls = clsp[b];
    for (int idx = t; idx < 576 * NCH; idx += 256) {
        int ci9 = (NCH == 2) ? (idx >> 1) : idx;
        int ch = (NCH == 2) ? (idx & 1) : 0;
        ldsf[WSEL_F + idx] = W3[(size_t)ci9 * C3TOT + cls * NCH + ch];
    }
    __syncthreads();

    // ================= conv3: 12x12 x NCH, VALU =================
    if (t < 144) {
        int py = t / 12, px = t - py * 12;
        int gy = ty0 + py, gx = tx0 + px;
        if (gy < 512 && gx < 512) {
            float a0 = 0.f, a1 = 0.f;
#pragma unroll
            for (int dy = 0; dy < 3; ++dy)
#pragma unroll
            for (int dx = 0; dx < 3; ++dx) {
                int hrow = (py + dy) * 14 + (px + dx);
                const ushort_t* hp = &lds[H2_E + hrow * 72];
                const float* wp = &ldsf[WSEL_F + (dy * 3 + dx) * 64 * NCH];
#pragma unroll
                for (int cb = 0; cb < 8; ++cb) {
                    short8 hv = *(const short8*)&hp[cb * 8];
#pragma unroll
                    for (int i = 0; i < 8; ++i) {
                        float xv = bf2f((ushort_t)hv[i]);
                        a0 += xv * wp[(cb * 8 + i) * NCH];
                        if (NCH == 2) a1 += xv * wp[(cb * 8 + i) * NCH + 1];
                    }
                }
            }
            size_t ob = (((size_t)b * 512 + gy) * 512 + gx) * NCH;
            outp[ob] = a0 + B3[cls * NCH + 0];
            if (NCH == 2) outp[ob + 1] = a1 + B3[cls * NCH + 1];
        }
    }
}

extern "C" void kernel_launch(void* const* d_in, const int* in_sizes, int n_in,
                              void* d_out, int out_size, void* d_ws, size_t ws_size,
                              hipStream_t stream) {
    const float* x0  = (const float*)d_in[0];
    const float* f4  = (const float*)d_in[1];
    const float* Wo1 = (const float*)d_in[2];  const float* bo1 = (const float*)d_in[3];
    const float* Wo2 = (const float*)d_in[4];  const float* bo2 = (const float*)d_in[5];
    const float* Wo3 = (const float*)d_in[6];  const float* bo3 = (const float*)d_in[7];
    const float* Ww1 = (const float*)d_in[8];  const float* bw1 = (const float*)d_in[9];
    const float* Ww2 = (const float*)d_in[10]; const float* bw2 = (const float*)d_in[11];
    const float* Ww3 = (const float*)d_in[12]; const float* bw3 = (const float*)d_in[13];
    const float* Wc1 = (const float*)d_in[14]; const float* bc1 = (const float*)d_in[15];
    const float* Wc2 = (const float*)d_in[16]; const float* bc2 = (const float*)d_in[17];
    const float* Wc3 = (const float*)d_in[18]; const float* bc3 = (const float*)d_in[19];

    float* out = (float*)d_out;
    float* offsets_out = out;                      // (4,512,512,2)
    float* weights_out = out + 2097152;            // (4,512,512,1)
    float* pred_out    = out + 3145728;            // (4,3)
    int* cls_ws = (int*)d_ws;

    cls_kernel<<<4, 1024, 0, stream>>>(f4, Wc1, bc1, Wc2, bc2, Wc3, bc3, pred_out, cls_ws);

    dim3 grid(43 * 43, 4);
    fused_branch<2, 6><<<grid, 256, 0, stream>>>(x0, Wo1, bo1, Wo2, bo2, Wo3, bo3,
                                                 cls_ws, offsets_out);
    fused_branch<1, 3><<<grid, 256, 0, stream>>>(x0, Ww1, bw1, Ww2, bw2, Ww3, bw3,
                                                 cls_ws, weights_out);
}

// Round 4
// 960.521 us; speedup vs baseline: 5.9132x; 1.3004x over previous
//
#include <hip/hip_runtime.h>
#include <math.h>

typedef __attribute__((ext_vector_type(8))) short short8;
typedef __attribute__((ext_vector_type(4))) float floatx4;
typedef unsigned short ushort_t;
typedef unsigned int uint_t;

__device__ __forceinline__ ushort_t f2bf(float x) {   // RNE f32 -> bf16
    uint_t u = __float_as_uint(x);
    uint_t r = (u + 0x7fffu + ((u >> 16) & 1u)) >> 16;
    return (ushort_t)r;
}
__device__ __forceinline__ float bf2f(ushort_t h) {
    return __uint_as_float(((uint_t)h) << 16);
}

// ---------------- weight prep: fp32 -> bf16, MFMA-tiled --------------------
// ws (ushort, after 16-byte cls slot):
//   W1o @ 0      (9 taps x 2048)   tile = [4 kslice][64 co][8 ci]
//   W2o @ 18432  (9 taps x 4096)   tile = [8 kslice][64 co][8 ci]
//   W1w @ 55296  (9 x 2048)
//   W2w @ 73728  (9 x 4096)        total 110592 ushort
__global__ void prep_weights(const float* __restrict__ W1a, const float* __restrict__ W2a,
                             const float* __restrict__ W1b, const float* __restrict__ W2b,
                             ushort_t* __restrict__ out) {
    int i = blockIdx.x * 256 + threadIdx.x;
    if (i >= 110592) return;
    const float* W; int off; int C;
    if (i < 18432)      { W = W1a; off = i;         C = 32; }
    else if (i < 55296) { W = W2a; off = i - 18432; C = 64; }
    else if (i < 73728) { W = W1b; off = i - 55296; C = 32; }
    else                { W = W2b; off = i - 73728; C = 64; }
    int pt = C * 64;                    // ushorts per tap tile
    int tap = off / pt, rem = off - tap * pt;
    int k4 = rem >> 9, rem2 = rem & 511;
    int co = rem2 >> 3, j = rem2 & 7;
    int ci = k4 * 8 + j;
    out[i] = f2bf(W[(size_t)(tap * C + ci) * 64 + co]);
}

// ---------------- classifier: gap -> 256x128 -> 128x128 -> 128x3 -----------
__global__ void cls_kernel(const float* __restrict__ f4,
                           const float* __restrict__ Wc1, const float* __restrict__ bc1,
                           const float* __restrict__ Wc2, const float* __restrict__ bc2,
                           const float* __restrict__ Wc3, const float* __restrict__ bc3,
                           float* __restrict__ pred_out, int* __restrict__ cls_out) {
    int b = blockIdx.x;
    int t = threadIdx.x;                       // 1024 threads
    __shared__ float4 part4[1024];
    __shared__ float gap[256];
    __shared__ float z1[128];
    __shared__ float z2[128];
    __shared__ float lg[3];
    const float* f = f4 + (size_t)b * 1024 * 256;
    int ci4 = t & 63, po = t >> 6;             // 64 float4-groups x 16 row-partitions
    float4 s = {0, 0, 0, 0};
    for (int p = po; p < 1024; p += 16) {
        float4 v = *(const float4*)&f[(size_t)p * 256 + ci4 * 4];
        s.x += v.x; s.y += v.y; s.z += v.z; s.w += v.w;
    }
    part4[po * 64 + ci4] = s;
    __syncthreads();
    if (t < 64) {
        float4 g = {0, 0, 0, 0};
        for (int p = 0; p < 16; ++p) {
            float4 v = part4[p * 64 + t];
            g.x += v.x; g.y += v.y; g.z += v.z; g.w += v.w;
        }
        gap[t * 4 + 0] = g.x * (1.0f / 1024.0f);
        gap[t * 4 + 1] = g.y * (1.0f / 1024.0f);
        gap[t * 4 + 2] = g.z * (1.0f / 1024.0f);
        gap[t * 4 + 3] = g.w * (1.0f / 1024.0f);
    }
    __syncthreads();
    if (t < 128) {
        float a = bc1[t];
        for (int i = 0; i < 256; ++i) a += gap[i] * Wc1[i * 128 + t];
        z1[t] = fmaxf(a, 0.f);
    }
    __syncthreads();
    if (t < 128) {
        float a = bc2[t];
        for (int i = 0; i < 128; ++i) a += z1[i] * Wc2[i * 128 + t];
        z2[t] = fmaxf(a, 0.f);
    }
    __syncthreads();
    if (t < 3) {
        float a = bc3[t];
        for (int i = 0; i < 128; ++i) a += z2[i] * Wc3[i * 3 + t];
        lg[t] = a;
    }
    __syncthreads();
    if (t == 0) {
        float m = fmaxf(lg[0], fmaxf(lg[1], lg[2]));
        float e0 = expf(lg[0] - m), e1 = expf(lg[1] - m), e2 = expf(lg[2] - m);
        float ssum = e0 + e1 + e2;
        pred_out[b * 3 + 0] = e0 / ssum;
        pred_out[b * 3 + 1] = e1 / ssum;
        pred_out[b * 3 + 2] = e2 / ssum;
        int idx = 0; float best = lg[0];
        if (lg[1] > best) { best = lg[1]; idx = 1; }
        if (lg[2] > best) { best = lg[2]; idx = 2; }
        cls_out[b] = idx;
    }
}

// ---------------- fused MFMA conv branch -----------------------------------
// 12x12 out tile. x0 18x18 -> h1 16x16 -> h2 14x14 -> out (selected ch).
// LDS (ushort). Padded kslice strides put the 4 q-lanes on banks +4 apart
// (stride S: q byte-step 2S; S=2600/2056/520 -> (2S/4)%32 = 4).
//   x0  [4 ks x 2600]           : [0, 10400)
//   h1  [8 ks x 2056]           : [10400, 26848)
//   Wd  2 bufs x 4160 (ks 520)  : [26848, 35168)
//   h2  [196 px][72]            : [0, 14112)     (x0/h1-head dead)
//   W3sel floats @ float-idx 13424 == Wd region  (Wd dead post-conv2)
#define X0_E 0
#define X0_KS 2600
#define H1_E 10400
#define H1_KS 2056
#define WD_E 26848
#define WD_BUF 4160
#define WD_KS 520
#define H2_E 0
#define WSEL_F 13424
#define LDS_E 35168

template<int NCH, int C3TOT>
__global__ __launch_bounds__(256, 2)
void fused_branch(const float* __restrict__ x0,
                  const ushort_t* __restrict__ W1t, const float* __restrict__ B1,
                  const ushort_t* __restrict__ W2t, const float* __restrict__ B2,
                  const float* __restrict__ W3, const float* __restrict__ B3,
                  const int* __restrict__ clsp,
                  float* __restrict__ outp) {
    __shared__ __align__(16) ushort_t lds[LDS_E];
    float* ldsf = (float*)lds;
    const int t = threadIdx.x;
    const int b = blockIdx.y;
    const int tileY = blockIdx.x / 43, tileX = blockIdx.x - tileY * 43;
    const int ty0 = tileY * 12, tx0 = tileX * 12;
    const int lane = t & 63, wave = t >> 6;
    const int m = lane & 15, q = lane >> 4;

    // ---- stage x0 (18x18x32 fp32 -> bf16 [4 ks][324 px][8]) ----
    for (int idx = t; idx < 1296; idx += 256) {
        int pix = idx >> 2, qq = idx & 3;
        int py = pix / 18, px = pix - py * 18;
        int gy = ty0 - 3 + py, gx = tx0 - 3 + px;
        float4 v0 = {0, 0, 0, 0}, v1 = {0, 0, 0, 0};
        if ((uint_t)gy < 512u && (uint_t)gx < 512u) {
            const float* xp = x0 + (((size_t)b * 512 + gy) * 512 + gx) * 32 + qq * 8;
            v0 = *(const float4*)xp;
            v1 = *(const float4*)(xp + 4);
        }
        short8 pk;
        pk[0] = f2bf(v0.x); pk[1] = f2bf(v0.y); pk[2] = f2bf(v0.z); pk[3] = f2bf(v0.w);
        pk[4] = f2bf(v1.x); pk[5] = f2bf(v1.y); pk[6] = f2bf(v1.z); pk[7] = f2bf(v1.w);
        *(short8*)&lds[X0_E + qq * X0_KS + pix * 8] = pk;
    }
    // stage W1 tap 0 (t*8 == kslice*512 + co*8 for kslice=t>>6, co=t&63)
    {
        short8 w = *(const short8*)&W1t[t * 8];
        *(short8*)&lds[WD_E + (t >> 6) * WD_KS + (t & 63) * 8] = w;
    }
    __syncthreads();

    // ================= conv1: h1(16x16x64) via MFMA =================
    {
        floatx4 acc[4][4];
#pragma unroll
        for (int mi = 0; mi < 4; ++mi)
#pragma unroll
            for (int n = 0; n < 4; ++n) acc[mi][n] = (floatx4){0.f, 0.f, 0.f, 0.f};

        for (int tap = 0; tap < 9; ++tap) {
            int buf = tap & 1;
            short8 wnext;
            if (tap < 8) wnext = *(const short8*)&W1t[(tap + 1) * 2048 + t * 8];
            int dy = tap / 3, dx = tap - dy * 3;
            short8 Bf[4];
#pragma unroll
            for (int n = 0; n < 4; ++n)
                Bf[n] = *(const short8*)&lds[WD_E + buf * WD_BUF + q * WD_KS + (n * 16 + m) * 8];
#pragma unroll
            for (int mi = 0; mi < 4; ++mi) {
                int Mt = wave + mi * 4;            // h1 row
                short8 A = *(const short8*)&lds[X0_E + q * X0_KS + ((Mt + dy) * 18 + (m + dx)) * 8];
#pragma unroll
                for (int n = 0; n < 4; ++n)
                    acc[mi][n] = __builtin_amdgcn_mfma_f32_16x16x32_bf16(A, Bf[n], acc[mi][n], 0, 0, 0);
            }
            if (tap < 8)
                *(short8*)&lds[WD_E + (buf ^ 1) * WD_BUF + (t >> 6) * WD_KS + (t & 63) * 8] = wnext;
            __syncthreads();
        }
        // epilogue: bias+relu+SAME-pad mask -> h1 [8 ks x 2056]
#pragma unroll
        for (int n = 0; n < 4; ++n) {
            int co = n * 16 + m;
            float bias = B1[co];
            ushort_t* hb = &lds[H1_E + (co >> 3) * H1_KS + (co & 7)];
#pragma unroll
            for (int mi = 0; mi < 4; ++mi) {
                int Mt = wave + mi * 4;
                int gy = ty0 - 2 + Mt;
#pragma unroll
                for (int r = 0; r < 4; ++r) {
                    int x = q * 4 + r;
                    int gx = tx0 - 2 + x;
                    bool ok = ((uint_t)gy < 512u) && ((uint_t)gx < 512u);
                    float v = fmaxf(acc[mi][n][r] + bias, 0.f);
                    hb[(Mt * 16 + x) * 8] = ok ? f2bf(v) : (ushort_t)0;
                }
            }
        }
    }
    // stage W2 tap 0
    __syncthreads();
    {
#pragma unroll
        for (int it = 0; it < 2; ++it) {
            int idx = t + it * 256;
            short8 w = *(const short8*)&W2t[idx * 8];
            *(short8*)&lds[WD_E + (idx >> 6) * WD_KS + (idx & 63) * 8] = w;
        }
    }
    __syncthreads();

    // ================= conv2: h2(14x14x64) via MFMA =================
    {
        floatx4 acc[4][4];
#pragma unroll
        for (int mi = 0; mi < 4; ++mi)
#pragma unroll
            for (int n = 0; n < 4; ++n) acc[mi][n] = (floatx4){0.f, 0.f, 0.f, 0.f};
        int hb2[4];
#pragma unroll
        for (int mi = 0; mi < 4; ++mi) {
            int p0 = (wave + mi * 4) * 16 + m;
            int py = p0 / 14, px = p0 - py * 14;
            hb2[mi] = py * 16 + px;
        }

        for (int tap = 0; tap < 9; ++tap) {
            int buf = tap & 1;
            short8 wn0, wn1;
            if (tap < 8) {
                wn0 = *(const short8*)&W2t[(tap + 1) * 4096 + t * 8];
                wn1 = *(const short8*)&W2t[(tap + 1) * 4096 + (t + 256) * 8];
            }
            int dy = tap / 3, dx = tap - dy * 3;
#pragma unroll
            for (int kh = 0; kh < 2; ++kh) {
                short8 Bf[4];
#pragma unroll
                for (int n = 0; n < 4; ++n)
                    Bf[n] = *(const short8*)&lds[WD_E + buf * WD_BUF + (kh * 4 + q) * WD_KS + (n * 16 + m) * 8];
#pragma unroll
                for (int mi = 0; mi < 4; ++mi) {
                    int Mt = wave + mi * 4;
                    if (Mt < 13) {
                        short8 A = *(const short8*)&lds[H1_E + (kh * 4 + q) * H1_KS + (hb2[mi] + dy * 16 + dx) * 8];
#pragma unroll
                        for (int n = 0; n < 4; ++n)
                            acc[mi][n] = __builtin_amdgcn_mfma_f32_16x16x32_bf16(A, Bf[n], acc[mi][n], 0, 0, 0);
                    }
                }
            }
            if (tap < 8) {
                int nb = buf ^ 1;
                *(short8*)&lds[WD_E + nb * WD_BUF + (t >> 6) * WD_KS + (t & 63) * 8] = wn0;
                *(short8*)&lds[WD_E + nb * WD_BUF + ((t + 256) >> 6) * WD_KS + (t & 63) * 8] = wn1;
            }
            __syncthreads();
        }
        // epilogue: bias+relu+mask -> h2 [196][72] (x0/h1-head dead)
#pragma unroll
        for (int n = 0; n < 4; ++n) {
            int co = n * 16 + m;
            float bias = B2[co];
#pragma unroll
            for (int mi = 0; mi < 4; ++mi) {
                int Mt = wave + mi * 4;
                if (Mt >= 13) continue;
#pragma unroll
                for (int r = 0; r < 4; ++r) {
                    int pixel = Mt * 16 + q * 4 + r;
                    if (pixel < 196) {
                        int py = pixel / 14, px = pixel - py * 14;
                        int gy = ty0 - 1 + py, gx = tx0 - 1 + px;
                        bool ok = ((uint_t)gy < 512u) && ((uint_t)gx < 512u);
                        float v = fmaxf(acc[mi][n][r] + bias, 0.f);
                        lds[H2_E + pixel * 72 + co] = ok ? f2bf(v) : (ushort_t)0;
                    }
                }
            }
        }
    }

    // ---- stage selected W3 channels (Wd region dead now) ----
    const int cls = clsp[b];
    for (int idx = t; idx < 576 * NCH; idx += 256) {
        int ci9 = (NCH == 2) ? (idx >> 1) : idx;
        int ch = (NCH == 2) ? (idx & 1) : 0;
        ldsf[WSEL_F + idx] = W3[(size_t)ci9 * C3TOT + cls * NCH + ch];
    }
    __syncthreads();

    // ================= conv3: 12x12 x NCH, VALU =================
    if (t < 144) {
        int py = t / 12, px = t - py * 12;
        int gy = ty0 + py, gx = tx0 + px;
        if (gy < 512 && gx < 512) {
            float a0 = 0.f, a1 = 0.f;
#pragma unroll
            for (int dy = 0; dy < 3; ++dy)
#pragma unroll
            for (int dx = 0; dx < 3; ++dx) {
                int hrow = (py + dy) * 14 + (px + dx);
                const ushort_t* hp = &lds[H2_E + hrow * 72];
                const float* wp = &ldsf[WSEL_F + (dy * 3 + dx) * 64 * NCH];
#pragma unroll
                for (int cb = 0; cb < 8; ++cb) {
                    short8 hv = *(const short8*)&hp[cb * 8];
#pragma unroll
                    for (int i = 0; i < 8; ++i) {
                        float xv = bf2f((ushort_t)hv[i]);
                        a0 += xv * wp[(cb * 8 + i) * NCH];
                        if (NCH == 2) a1 += xv * wp[(cb * 8 + i) * NCH + 1];
                    }
                }
            }
            size_t ob = (((size_t)b * 512 + gy) * 512 + gx) * NCH;
            outp[ob] = a0 + B3[cls * NCH + 0];
            if (NCH == 2) outp[ob + 1] = a1 + B3[cls * NCH + 1];
        }
    }
}

extern "C" void kernel_launch(void* const* d_in, const int* in_sizes, int n_in,
                              void* d_out, int out_size, void* d_ws, size_t ws_size,
                              hipStream_t stream) {
    const float* x0  = (const float*)d_in[0];
    const float* f4  = (const float*)d_in[1];
    const float* Wo1 = (const float*)d_in[2];  const float* bo1 = (const float*)d_in[3];
    const float* Wo2 = (const float*)d_in[4];  const float* bo2 = (const float*)d_in[5];
    const float* Wo3 = (const float*)d_in[6];  const float* bo3 = (const float*)d_in[7];
    const float* Ww1 = (const float*)d_in[8];  const float* bw1 = (const float*)d_in[9];
    const float* Ww2 = (const float*)d_in[10]; const float* bw2 = (const float*)d_in[11];
    const float* Ww3 = (const float*)d_in[12]; const float* bw3 = (const float*)d_in[13];
    const float* Wc1 = (const float*)d_in[14]; const float* bc1 = (const float*)d_in[15];
    const float* Wc2 = (const float*)d_in[16]; const float* bc2 = (const float*)d_in[17];
    const float* Wc3 = (const float*)d_in[18]; const float* bc3 = (const float*)d_in[19];

    float* out = (float*)d_out;
    float* offsets_out = out;                      // (4,512,512,2)
    float* weights_out = out + 2097152;            // (4,512,512,1)
    float* pred_out    = out + 3145728;            // (4,3)
    int* cls_ws = (int*)d_ws;
    ushort_t* wt = (ushort_t*)((char*)d_ws + 16);  // tiled bf16 weights (216 KB)
    const ushort_t* W1o_t = wt;
    const ushort_t* W2o_t = wt + 18432;
    const ushort_t* W1w_t = wt + 55296;
    const ushort_t* W2w_t = wt + 73728;

    prep_weights<<<432, 256, 0, stream>>>(Wo1, Wo2, Ww1, Ww2, wt);
    cls_kernel<<<4, 1024, 0, stream>>>(f4, Wc1, bc1, Wc2, bc2, Wc3, bc3, pred_out, cls_ws);

    dim3 grid(43 * 43, 4);
    fused_branch<2, 6><<<grid, 256, 0, stream>>>(x0, W1o_t, bo1, W2o_t, bo2, Wo3, bo3,
                                                 cls_ws, offsets_out);
    fused_branch<1, 3><<<grid, 256, 0, stream>>>(x0, W1w_t, bw1, W2w_t, bw2, Ww3, bw3,
                                                 cls_ws, weights_out);
}

// Round 5
// 797.487 us; speedup vs baseline: 7.1220x; 1.2044x over previous
//
#include <hip/hip_runtime.h>
#include <math.h>

typedef __attribute__((ext_vector_type(8))) short short8;
typedef __attribute__((ext_vector_type(4))) short short4v;
typedef __attribute__((ext_vector_type(4))) float floatx4;
typedef unsigned short ushort_t;
typedef unsigned int uint_t;

__device__ __forceinline__ ushort_t f2bf(float x) {   // RNE f32 -> bf16
    uint_t u = __float_as_uint(x);
    uint_t r = (u + 0x7fffu + ((u >> 16) & 1u)) >> 16;
    return (ushort_t)r;
}
__device__ __forceinline__ short4v pack4(float a, float b, float c, float d) {
    short4v r;
    r[0] = (short)f2bf(a); r[1] = (short)f2bf(b);
    r[2] = (short)f2bf(c); r[3] = (short)f2bf(d);
    return r;
}

// ---------------- weight prep: fp32 -> bf16, MFMA-tiled --------------------
// tile = [ci/8 kslice][64 co][8 ci]
__global__ void prep_weights(const float* __restrict__ W1a, const float* __restrict__ W2a,
                             const float* __restrict__ W1b, const float* __restrict__ W2b,
                             ushort_t* __restrict__ out) {
    int i = blockIdx.x * 256 + threadIdx.x;
    if (i >= 110592) return;
    const float* W; int off; int C;
    if (i < 18432)      { W = W1a; off = i;         C = 32; }
    else if (i < 55296) { W = W2a; off = i - 18432; C = 64; }
    else if (i < 73728) { W = W1b; off = i - 55296; C = 32; }
    else                { W = W2b; off = i - 73728; C = 64; }
    int pt = C * 64;
    int tap = off / pt, rem = off - tap * pt;
    int k4 = rem >> 9, rem2 = rem & 511;
    int co = rem2 >> 3, j = rem2 & 7;
    int ci = k4 * 8 + j;
    out[i] = f2bf(W[(size_t)(tap * C + ci) * 64 + co]);
}

// ---------------- classifier, stage 1: partial GAP -------------------------
__global__ void gap_partial(const float* __restrict__ f4, float* __restrict__ part) {
    int c = blockIdx.x, b = blockIdx.y, t = threadIdx.x;
    __shared__ float4 red[256];
    int ci4 = t & 63, po = t >> 6;
    const float* f = f4 + ((size_t)b * 1024 + c * 128) * 256;
    float4 s = {0, 0, 0, 0};
    for (int i = 0; i < 32; ++i) {
        float4 v = *(const float4*)&f[(size_t)(i * 4 + po) * 256 + ci4 * 4];
        s.x += v.x; s.y += v.y; s.z += v.z; s.w += v.w;
    }
    red[t] = s;
    __syncthreads();
    if (t < 64) {
        float4 a = red[t], b2 = red[64 + t], c2 = red[128 + t], d2 = red[192 + t];
        float4 g;
        g.x = a.x + b2.x + c2.x + d2.x;
        g.y = a.y + b2.y + c2.y + d2.y;
        g.z = a.z + b2.z + c2.z + d2.z;
        g.w = a.w + b2.w + c2.w + d2.w;
        *(float4*)&part[((b * 8 + c) << 8) + t * 4] = g;
    }
}

// ---------------- classifier, stage 2: MLP + softmax + argmax --------------
__global__ void cls_finish(const float* __restrict__ part,
                           const float* __restrict__ Wc1, const float* __restrict__ bc1,
                           const float* __restrict__ Wc2, const float* __restrict__ bc2,
                           const float* __restrict__ Wc3, const float* __restrict__ bc3,
                           float* __restrict__ pred_out, int* __restrict__ cls_out) {
    int b = blockIdx.x;
    int t = threadIdx.x;                       // 256 threads
    __shared__ float gap[256];
    __shared__ float z1[128];
    __shared__ float z2[128];
    __shared__ float lg[3];
    float s = 0.f;
    for (int c = 0; c < 8; ++c) s += part[((b * 8 + c) << 8) + t];
    gap[t] = s * (1.0f / 1024.0f);
    __syncthreads();
    if (t < 128) {
        float a = bc1[t];
        for (int i = 0; i < 256; ++i) a += gap[i] * Wc1[i * 128 + t];
        z1[t] = fmaxf(a, 0.f);
    }
    __syncthreads();
    if (t < 128) {
        float a = bc2[t];
        for (int i = 0; i < 128; ++i) a += z1[i] * Wc2[i * 128 + t];
        z2[t] = fmaxf(a, 0.f);
    }
    __syncthreads();
    if (t < 3) {
        float a = bc3[t];
        for (int i = 0; i < 128; ++i) a += z2[i] * Wc3[i * 3 + t];
        lg[t] = a;
    }
    __syncthreads();
    if (t == 0) {
        float m = fmaxf(lg[0], fmaxf(lg[1], lg[2]));
        float e0 = expf(lg[0] - m), e1 = expf(lg[1] - m), e2 = expf(lg[2] - m);
        float ssum = e0 + e1 + e2;
        pred_out[b * 3 + 0] = e0 / ssum;
        pred_out[b * 3 + 1] = e1 / ssum;
        pred_out[b * 3 + 2] = e2 / ssum;
        int idx = 0; float best = lg[0];
        if (lg[1] > best) { best = lg[1]; idx = 1; }
        if (lg[2] > best) { best = lg[2]; idx = 2; }
        cls_out[b] = idx;
    }
}

// ---------------- fused MFMA conv branch -----------------------------------
// Operand roles: A = weights [co][ci], B = pixels [ci][px].
// C/D: row (q*4+reg) = co-within-16, col (lane&15) = pixel -> each lane holds
// 4 CONSECUTIVE co per pixel -> packed b64 epilogue stores.
// LDS (ushort):
//   x0  [4 ks x 2600]           : [0, 10400)
//   h1  [8 ks x 2056]           : [10400, 26848)
//   Wd  2 bufs x 4160 (ks 520)  : [26848, 35168)
//   h2  [196 px][72]            : [0, 14112)      (x0/h1-head dead post-conv2)
//   W3A [18 k2][4 q][16 ch][8]  : [14112, 23328)  (dead h1)
//   SF  float partials 1152     : ushort [23328, 25632)
#define X0_E 0
#define X0_KS 2600
#define H1_E 10400
#define H1_KS 2056
#define WD_E 26848
#define WD_BUF 4160
#define WD_KS 520
#define H2_E 0
#define W3A_E 14112
#define SF_F 11664
#define LDS_E 35168

template<int NCH, int C3TOT>
__global__ __launch_bounds__(256, 2)
void fused_branch(const float* __restrict__ x0,
                  const ushort_t* __restrict__ W1t, const float* __restrict__ B1,
                  const ushort_t* __restrict__ W2t, const float* __restrict__ B2,
                  const float* __restrict__ W3, const float* __restrict__ B3,
                  const int* __restrict__ clsp,
                  float* __restrict__ outp) {
    __shared__ __align__(16) ushort_t lds[LDS_E];
    float* ldsf = (float*)lds;
    const int t = threadIdx.x;
    const int b = blockIdx.y;
    const int tileY = blockIdx.x / 43, tileX = blockIdx.x - tileY * 43;
    const int ty0 = tileY * 12, tx0 = tileX * 12;
    const int lane = t & 63, wave = t >> 6;
    const int m = lane & 15, q = lane >> 4;

    // ---- stage x0 (18x18x32 fp32 -> bf16 [4 ks][324 px][8]) ----
    for (int idx = t; idx < 1296; idx += 256) {
        int pix = idx >> 2, qq = idx & 3;
        int py = pix / 18, px = pix - py * 18;
        int gy = ty0 - 3 + py, gx = tx0 - 3 + px;
        float4 v0 = {0, 0, 0, 0}, v1 = {0, 0, 0, 0};
        if ((uint_t)gy < 512u && (uint_t)gx < 512u) {
            const float* xp = x0 + (((size_t)b * 512 + gy) * 512 + gx) * 32 + qq * 8;
            v0 = *(const float4*)xp;
            v1 = *(const float4*)(xp + 4);
        }
        short8 pk;
        pk[0] = f2bf(v0.x); pk[1] = f2bf(v0.y); pk[2] = f2bf(v0.z); pk[3] = f2bf(v0.w);
        pk[4] = f2bf(v1.x); pk[5] = f2bf(v1.y); pk[6] = f2bf(v1.z); pk[7] = f2bf(v1.w);
        *(short8*)&lds[X0_E + qq * X0_KS + pix * 8] = pk;
    }
    // stage W1 tap 0
    {
        short8 w = *(const short8*)&W1t[t * 8];
        *(short8*)&lds[WD_E + (t >> 6) * WD_KS + (t & 63) * 8] = w;
    }
    __syncthreads();

    // ================= conv1: h1(16x16x64) =================
    {
        floatx4 acc[4][4];
#pragma unroll
        for (int mi = 0; mi < 4; ++mi)
#pragma unroll
            for (int n = 0; n < 4; ++n) acc[mi][n] = (floatx4){0.f, 0.f, 0.f, 0.f};

        for (int tap = 0; tap < 9; ++tap) {
            int buf = tap & 1;
            short8 wnext;
            if (tap < 8) wnext = *(const short8*)&W1t[(tap + 1) * 2048 + t * 8];
            int dy = tap / 3, dx = tap - dy * 3;
            short8 Af[4], Bx[4];
#pragma unroll
            for (int mi = 0; mi < 4; ++mi)
                Af[mi] = *(const short8*)&lds[WD_E + buf * WD_BUF + q * WD_KS + (mi * 16 + m) * 8];
#pragma unroll
            for (int n = 0; n < 4; ++n) {
                int ptile = n * 4 + wave;         // h1 row
                Bx[n] = *(const short8*)&lds[X0_E + q * X0_KS + ((ptile + dy) * 18 + (m + dx)) * 8];
            }
#pragma unroll
            for (int mi = 0; mi < 4; ++mi)
#pragma unroll
                for (int n = 0; n < 4; ++n)
                    acc[mi][n] = __builtin_amdgcn_mfma_f32_16x16x32_bf16(Af[mi], Bx[n], acc[mi][n], 0, 0, 0);
            if (tap < 8)
                *(short8*)&lds[WD_E + (buf ^ 1) * WD_BUF + (t >> 6) * WD_KS + (t & 63) * 8] = wnext;
            __syncthreads();
        }
        // epilogue: bias+relu+SAME-pad mask -> h1, packed b64 stores
#pragma unroll
        for (int mi = 0; mi < 4; ++mi) {
            float4 bb = *(const float4*)&B1[mi * 16 + q * 4];
            int ks = mi * 2 + (q >> 1), lo = (q & 1) * 4;
#pragma unroll
            for (int n = 0; n < 4; ++n) {
                int ptile = n * 4 + wave;
                int gy = ty0 - 2 + ptile, gx = tx0 - 2 + m;
                bool ok = ((uint_t)gy < 512u) && ((uint_t)gx < 512u);
                floatx4 a = acc[mi][n];
                float v0 = ok ? fmaxf(a[0] + bb.x, 0.f) : 0.f;
                float v1 = ok ? fmaxf(a[1] + bb.y, 0.f) : 0.f;
                float v2 = ok ? fmaxf(a[2] + bb.z, 0.f) : 0.f;
                float v3 = ok ? fmaxf(a[3] + bb.w, 0.f) : 0.f;
                *(short4v*)&lds[H1_E + ks * H1_KS + (ptile * 16 + m) * 8 + lo] = pack4(v0, v1, v2, v3);
            }
        }
    }
    __syncthreads();
    // stage W2 tap 0
    {
#pragma unroll
        for (int it = 0; it < 2; ++it) {
            int idx = t + it * 256;
            short8 w = *(const short8*)&W2t[idx * 8];
            *(short8*)&lds[WD_E + (idx >> 6) * WD_KS + (idx & 63) * 8] = w;
        }
    }
    __syncthreads();

    // ================= conv2: h2(14x14x64) =================
    {
        floatx4 acc[4][4];
#pragma unroll
        for (int mi = 0; mi < 4; ++mi)
#pragma unroll
            for (int n = 0; n < 4; ++n) acc[mi][n] = (floatx4){0.f, 0.f, 0.f, 0.f};
        int hb2[4];
#pragma unroll
        for (int n = 0; n < 4; ++n) {
            int p0 = (n * 4 + wave) * 16 + m;
            int py = p0 / 14, px = p0 - py * 14;
            hb2[n] = py * 16 + px;
        }

        for (int tap = 0; tap < 9; ++tap) {
            int buf = tap & 1;
            short8 wn0, wn1;
            if (tap < 8) {
                wn0 = *(const short8*)&W2t[(tap + 1) * 4096 + t * 8];
                wn1 = *(const short8*)&W2t[(tap + 1) * 4096 + (t + 256) * 8];
            }
            int dy = tap / 3, dx = tap - dy * 3;
#pragma unroll
            for (int kh = 0; kh < 2; ++kh) {
                short8 Af[4], Bx[4];
#pragma unroll
                for (int mi = 0; mi < 4; ++mi)
                    Af[mi] = *(const short8*)&lds[WD_E + buf * WD_BUF + (kh * 4 + q) * WD_KS + (mi * 16 + m) * 8];
#pragma unroll
                for (int n = 0; n < 4; ++n)
                    Bx[n] = *(const short8*)&lds[H1_E + (kh * 4 + q) * H1_KS + (hb2[n] + dy * 16 + dx) * 8];
#pragma unroll
                for (int mi = 0; mi < 4; ++mi)
#pragma unroll
                    for (int n = 0; n < 4; ++n) {
                        int ptile = n * 4 + wave;
                        if (ptile < 13)
                            acc[mi][n] = __builtin_amdgcn_mfma_f32_16x16x32_bf16(Af[mi], Bx[n], acc[mi][n], 0, 0, 0);
                    }
            }
            if (tap < 8) {
                int nb = buf ^ 1;
                *(short8*)&lds[WD_E + nb * WD_BUF + (t >> 6) * WD_KS + (t & 63) * 8] = wn0;
                *(short8*)&lds[WD_E + nb * WD_BUF + ((t + 256) >> 6) * WD_KS + (t & 63) * 8] = wn1;
            }
            __syncthreads();
        }
        // epilogue: bias+relu+mask -> h2 [196][72], packed b64 stores
        float4 bbv[4];
#pragma unroll
        for (int mi = 0; mi < 4; ++mi) bbv[mi] = *(const float4*)&B2[mi * 16 + q * 4];
#pragma unroll
        for (int n = 0; n < 4; ++n) {
            int ptile = n * 4 + wave;
            if (ptile >= 13) continue;
            int p = ptile * 16 + m;
            bool pok = p < 196;
            int py = p / 14, px = p - py * 14;
            int gy = ty0 - 1 + py, gx = tx0 - 1 + px;
            bool ok = pok && ((uint_t)gy < 512u) && ((uint_t)gx < 512u);
#pragma unroll
            for (int mi = 0; mi < 4; ++mi) {
                floatx4 a = acc[mi][n];
                float4 bb = bbv[mi];
                float v0 = ok ? fmaxf(a[0] + bb.x, 0.f) : 0.f;
                float v1 = ok ? fmaxf(a[1] + bb.y, 0.f) : 0.f;
                float v2 = ok ? fmaxf(a[2] + bb.z, 0.f) : 0.f;
                float v3 = ok ? fmaxf(a[3] + bb.w, 0.f) : 0.f;
                if (pok)
                    *(short4v*)&lds[H2_E + p * 72 + mi * 16 + q * 4] = pack4(v0, v1, v2, v3);
            }
        }
    }
    // ---- W3A zero-fill (same phase as h2 epilogue; disjoint regions) ----
    {
        short8 z = {0, 0, 0, 0, 0, 0, 0, 0};
        for (int i = t; i < 1152; i += 256)
            *(short8*)&lds[W3A_E + i * 8] = z;
    }
    __syncthreads();
    // ---- W3A value fill: rows ch<NCH of [18 k2][4 q][16 ch][8] ----
    const int cls = clsp[b];
    for (int i = t; i < 576 * NCH; i += 256) {
        int j = i & 7, rest = i >> 3;
        int ch = rest % NCH, rest2 = rest / NCH;
        int qq = rest2 & 3, t2 = rest2 >> 2;
        int tap = t2 >> 1, kh = t2 & 1;
        int ci = kh * 32 + qq * 8 + j;
        lds[W3A_E + t2 * 512 + qq * 128 + ch * 8 + j] =
            f2bf(W3[(size_t)(tap * 64 + ci) * C3TOT + cls * NCH + ch]);
    }
    __syncthreads();

    // ================= conv3 via MFMA: rows=out-ch, cols=pixels ============
    {
        floatx4 acc3[9];
#pragma unroll
        for (int n = 0; n < 9; ++n) acc3[n] = (floatx4){0.f, 0.f, 0.f, 0.f};
        int hb3[9];
#pragma unroll
        for (int n = 0; n < 9; ++n) {
            int p = n * 16 + m;
            int py = p / 12, px = p - py * 12;
            hb3[n] = py * 14 + px;
        }
        for (int t2 = wave; t2 < 18; t2 += 4) {
            int tap = t2 >> 1, kh = t2 & 1;
            int dy = tap / 3, dx = tap - dy * 3;
            short8 Aw = *(const short8*)&lds[W3A_E + t2 * 512 + q * 128 + m * 8];
#pragma unroll
            for (int n = 0; n < 9; ++n) {
                short8 Bh = *(const short8*)&lds[H2_E + (hb3[n] + dy * 14 + dx) * 72 + kh * 32 + q * 8];
                acc3[n] = __builtin_amdgcn_mfma_f32_16x16x32_bf16(Aw, Bh, acc3[n], 0, 0, 0);
            }
        }
        // partial store: rows 0,1 live in lanes q==0, regs 0,1
        float* sf = ldsf + SF_F;
        if (q == 0) {
#pragma unroll
            for (int n = 0; n < 9; ++n) {
                float2 v = {acc3[n][0], acc3[n][1]};
                *(float2*)&sf[wave * 288 + n * 32 + m * 2] = v;
            }
        }
    }
    __syncthreads();
    if (t < 144) {
        float* sf = ldsf + SF_F;
        int p = t;
        int base = (p >> 4) * 32 + (p & 15) * 2;
        float a0 = sf[base] + sf[288 + base] + sf[576 + base] + sf[864 + base];
        int py = p / 12, px = p - py * 12;
        int gy = ty0 + py, gx = tx0 + px;
        if (gy < 512 && gx < 512) {
            size_t ob = (((size_t)b * 512 + gy) * 512 + gx) * NCH;
            outp[ob] = a0 + B3[cls * NCH + 0];
            if (NCH == 2) {
                float a1 = sf[base + 1] + sf[288 + base + 1] + sf[576 + base + 1] + sf[864 + base + 1];
                outp[ob + 1] = a1 + B3[cls * NCH + 1];
            }
        }
    }
}

extern "C" void kernel_launch(void* const* d_in, const int* in_sizes, int n_in,
                              void* d_out, int out_size, void* d_ws, size_t ws_size,
                              hipStream_t stream) {
    const float* x0  = (const float*)d_in[0];
    const float* f4  = (const float*)d_in[1];
    const float* Wo1 = (const float*)d_in[2];  const float* bo1 = (const float*)d_in[3];
    const float* Wo2 = (const float*)d_in[4];  const float* bo2 = (const float*)d_in[5];
    const float* Wo3 = (const float*)d_in[6];  const float* bo3 = (const float*)d_in[7];
    const float* Ww1 = (const float*)d_in[8];  const float* bw1 = (const float*)d_in[9];
    const float* Ww2 = (const float*)d_in[10]; const float* bw2 = (const float*)d_in[11];
    const float* Ww3 = (const float*)d_in[12]; const float* bw3 = (const float*)d_in[13];
    const float* Wc1 = (const float*)d_in[14]; const float* bc1 = (const float*)d_in[15];
    const float* Wc2 = (const float*)d_in[16]; const float* bc2 = (const float*)d_in[17];
    const float* Wc3 = (const float*)d_in[18]; const float* bc3 = (const float*)d_in[19];

    float* out = (float*)d_out;
    float* offsets_out = out;                      // (4,512,512,2)
    float* weights_out = out + 2097152;            // (4,512,512,1)
    float* pred_out    = out + 3145728;            // (4,3)
    int* cls_ws = (int*)d_ws;
    ushort_t* wt = (ushort_t*)((char*)d_ws + 16);  // tiled bf16 weights (216 KB)
    const ushort_t* W1o_t = wt;
    const ushort_t* W2o_t = wt + 18432;
    const ushort_t* W1w_t = wt + 55296;
    const ushort_t* W2w_t = wt + 73728;
    float* gap_part = (float*)((char*)d_ws + 221440);   // 4x8x256 floats (32 KB)

    prep_weights<<<432, 256, 0, stream>>>(Wo1, Wo2, Ww1, Ww2, wt);
    gap_partial<<<dim3(8, 4), 256, 0, stream>>>(f4, gap_part);
    cls_finish<<<4, 256, 0, stream>>>(gap_part, Wc1, bc1, Wc2, bc2, Wc3, bc3, pred_out, cls_ws);

    dim3 grid(43 * 43, 4);
    fused_branch<2, 6><<<grid, 256, 0, stream>>>(x0, W1o_t, bo1, W2o_t, bo2, Wo3, bo3,
                                                 cls_ws, offsets_out);
    fused_branch<1, 3><<<grid, 256, 0, stream>>>(x0, W1w_t, bw1, W2w_t, bw2, Ww3, bw3,
                                                 cls_ws, weights_out);
}

// Round 6
// 768.663 us; speedup vs baseline: 7.3891x; 1.0375x over previous
//
#include <hip/hip_runtime.h>
#include <hip/hip_bf16.h>
#include <math.h>

typedef __attribute__((ext_vector_type(8))) short short8;
typedef __attribute__((ext_vector_type(4))) short short4v;
typedef __attribute__((ext_vector_type(4))) float floatx4;
typedef unsigned short ushort_t;
typedef unsigned int uint_t;

__device__ __forceinline__ ushort_t f2bf(float x) {   // RNE f32 -> bf16
    uint_t u = __float_as_uint(x);
    uint_t r = (u + 0x7fffu + ((u >> 16) & 1u)) >> 16;
    return (ushort_t)r;
}
// HW-packed RNE conversion: 2 floats -> packed bf16x2 (v_cvt_pk_bf16_f32)
__device__ __forceinline__ short4v pack4(float a, float b, float c, float d) {
    union { __hip_bfloat162 h; uint_t u; } lo, hi;
    lo.h = __float22bfloat162_rn(make_float2(a, b));
    hi.h = __float22bfloat162_rn(make_float2(c, d));
    short4v r;
    r[0] = (short)(lo.u & 0xffffu); r[1] = (short)(lo.u >> 16);
    r[2] = (short)(hi.u & 0xffffu); r[3] = (short)(hi.u >> 16);
    return r;
}
__device__ __forceinline__ short8 pack8(float4 v0, float4 v1) {
    short4v lo = pack4(v0.x, v0.y, v0.z, v0.w);
    short4v hi = pack4(v1.x, v1.y, v1.z, v1.w);
    short8 pk;
    pk[0] = lo[0]; pk[1] = lo[1]; pk[2] = lo[2]; pk[3] = lo[3];
    pk[4] = hi[0]; pk[5] = hi[1]; pk[6] = hi[2]; pk[7] = hi[3];
    return pk;
}

// ---------------- prep: weights fp32->bf16 MFMA-tiled  +  partial GAP ------
// blocks [0,432): weight tiling; blocks [432,464): GAP partials
__global__ void prep_all(const float* __restrict__ W1a, const float* __restrict__ W2a,
                         const float* __restrict__ W1b, const float* __restrict__ W2b,
                         ushort_t* __restrict__ wt,
                         const float* __restrict__ f4, float* __restrict__ part) {
    __shared__ float4 red[256];
    int bi = blockIdx.x, t = threadIdx.x;
    if (bi < 432) {
        int i = bi * 256 + t;
        if (i >= 110592) return;
        const float* W; int off; int C;
        if (i < 18432)      { W = W1a; off = i;         C = 32; }
        else if (i < 55296) { W = W2a; off = i - 18432; C = 64; }
        else if (i < 73728) { W = W1b; off = i - 55296; C = 32; }
        else                { W = W2b; off = i - 73728; C = 64; }
        int pt = C * 64;
        int tap = off / pt, rem = off - tap * pt;
        int k4 = rem >> 9, rem2 = rem & 511;
        int co = rem2 >> 3, j = rem2 & 7;
        int ci = k4 * 8 + j;
        wt[i] = f2bf(W[(size_t)(tap * C + ci) * 64 + co]);
    } else {
        int g = bi - 432;
        int c = g & 7, b = g >> 3;
        int ci4 = t & 63, po = t >> 6;
        const float* f = f4 + ((size_t)b * 1024 + c * 128) * 256;
        float4 s = {0, 0, 0, 0};
        for (int i = 0; i < 32; ++i) {
            float4 v = *(const float4*)&f[(size_t)(i * 4 + po) * 256 + ci4 * 4];
            s.x += v.x; s.y += v.y; s.z += v.z; s.w += v.w;
        }
        red[t] = s;
        __syncthreads();
        if (t < 64) {
            float4 a = red[t], b2 = red[64 + t], c2 = red[128 + t], d2 = red[192 + t];
            float4 gg;
            gg.x = a.x + b2.x + c2.x + d2.x;
            gg.y = a.y + b2.y + c2.y + d2.y;
            gg.z = a.z + b2.z + c2.z + d2.z;
            gg.w = a.w + b2.w + c2.w + d2.w;
            *(float4*)&part[((b * 8 + c) << 8) + t * 4] = gg;
        }
    }
}

// ---------------- classifier finish: MLP + softmax + argmax ----------------
__global__ void cls_finish(const float* __restrict__ part,
                           const float* __restrict__ Wc1, const float* __restrict__ bc1,
                           const float* __restrict__ Wc2, const float* __restrict__ bc2,
                           const float* __restrict__ Wc3, const float* __restrict__ bc3,
                           float* __restrict__ pred_out, int* __restrict__ cls_out) {
    int b = blockIdx.x;
    int t = threadIdx.x;                       // 256 threads
    __shared__ float gap[256];
    __shared__ float z1[128];
    __shared__ float z2[128];
    __shared__ float lg[3];
    float s = 0.f;
    for (int c = 0; c < 8; ++c) s += part[((b * 8 + c) << 8) + t];
    gap[t] = s * (1.0f / 1024.0f);
    __syncthreads();
    if (t < 128) {
        float a = bc1[t];
        for (int i = 0; i < 256; ++i) a += gap[i] * Wc1[i * 128 + t];
        z1[t] = fmaxf(a, 0.f);
    }
    __syncthreads();
    if (t < 128) {
        float a = bc2[t];
        for (int i = 0; i < 128; ++i) a += z1[i] * Wc2[i * 128 + t];
        z2[t] = fmaxf(a, 0.f);
    }
    __syncthreads();
    if (t < 3) {
        float a = bc3[t];
        for (int i = 0; i < 128; ++i) a += z2[i] * Wc3[i * 3 + t];
        lg[t] = a;
    }
    __syncthreads();
    if (t == 0) {
        float m = fmaxf(lg[0], fmaxf(lg[1], lg[2]));
        float e0 = expf(lg[0] - m), e1 = expf(lg[1] - m), e2 = expf(lg[2] - m);
        float ssum = e0 + e1 + e2;
        pred_out[b * 3 + 0] = e0 / ssum;
        pred_out[b * 3 + 1] = e1 / ssum;
        pred_out[b * 3 + 2] = e2 / ssum;
        int idx = 0; float best = lg[0];
        if (lg[1] > best) { best = lg[1]; idx = 1; }
        if (lg[2] > best) { best = lg[2]; idx = 2; }
        cls_out[b] = idx;
    }
}

// ---------------- fused MFMA conv branch (both branches, grid.z) -----------
// A = weights [co][ci], B = pixels [ci][px]. C/D: row=co-within-16, col=pixel.
// LDS (ushort):
//   x0  [4 ks x 2600]           : [0, 10400)
//   h1  [8 ks x 2056]           : [10400, 26848)
//   Wd  2 bufs x 4160 (ks 520)  : [26848, 35168)
//   h2  [196 px][72]            : [0, 14112)      (x0/h1-head dead post-conv2)
//   W3A [18 k2][4 q][16 ch][8]  : [14112, 23328)  (dead h1)
//   SF  float partials 1152     : ushort [23328, 25632)
#define X0_E 0
#define X0_KS 2600
#define H1_E 10400
#define H1_KS 2056
#define WD_E 26848
#define WD_BUF 4160
#define WD_KS 520
#define H2_E 0
#define W3A_E 14112
#define SF_F 11664
#define LDS_E 35168

__global__ __launch_bounds__(256, 2)
void fused_branch(const float* __restrict__ x0,
                  const ushort_t* __restrict__ W1o_t, const ushort_t* __restrict__ W2o_t,
                  const ushort_t* __restrict__ W1w_t, const ushort_t* __restrict__ W2w_t,
                  const float* __restrict__ bo1, const float* __restrict__ bo2,
                  const float* __restrict__ bw1, const float* __restrict__ bw2,
                  const float* __restrict__ Wo3, const float* __restrict__ bo3,
                  const float* __restrict__ Ww3, const float* __restrict__ bw3,
                  const int* __restrict__ clsp,
                  float* __restrict__ off_out, float* __restrict__ w_out) {
    __shared__ __align__(16) ushort_t lds[LDS_E];
    float* ldsf = (float*)lds;
    const int t = threadIdx.x;
    const int b = blockIdx.y;
    const int z = blockIdx.z;
    const ushort_t* W1t = z ? W1w_t : W1o_t;
    const ushort_t* W2t = z ? W2w_t : W2o_t;
    const float* B1 = z ? bw1 : bo1;
    const float* B2 = z ? bw2 : bo2;
    const float* W3 = z ? Ww3 : Wo3;
    const float* B3 = z ? bw3 : bo3;
    float* outp = z ? w_out : off_out;
    const int NCH = z ? 1 : 2;
    const int C3TOT = z ? 3 : 6;

    const int tileY = blockIdx.x / 43, tileX = blockIdx.x - tileY * 43;
    const int ty0 = tileY * 12, tx0 = tileX * 12;
    const bool edge = (tileY == 0) | (tileY == 42) | (tileX == 0) | (tileX == 42);
    const int lane = t & 63, wave = t >> 6;
    const int m = lane & 15, q = lane >> 4;

    // ---- stage x0 (18x18x32 fp32 -> bf16 [4 ks][324 px][8]) ----
    if (!edge) {
        for (int idx = t; idx < 1296; idx += 256) {
            int pix = idx >> 2, qq = idx & 3;
            int py = pix / 18, px = pix - py * 18;
            const float* xp = x0 + (((size_t)b * 512 + (ty0 - 3 + py)) * 512 + (tx0 - 3 + px)) * 32 + qq * 8;
            *(short8*)&lds[X0_E + qq * X0_KS + pix * 8] =
                pack8(*(const float4*)xp, *(const float4*)(xp + 4));
        }
    } else {
        for (int idx = t; idx < 1296; idx += 256) {
            int pix = idx >> 2, qq = idx & 3;
            int py = pix / 18, px = pix - py * 18;
            int gy = ty0 - 3 + py, gx = tx0 - 3 + px;
            float4 v0 = {0, 0, 0, 0}, v1 = {0, 0, 0, 0};
            if ((uint_t)gy < 512u && (uint_t)gx < 512u) {
                const float* xp = x0 + (((size_t)b * 512 + gy) * 512 + gx) * 32 + qq * 8;
                v0 = *(const float4*)xp;
                v1 = *(const float4*)(xp + 4);
            }
            *(short8*)&lds[X0_E + qq * X0_KS + pix * 8] = pack8(v0, v1);
        }
    }
    // stage W1 tap 0
    {
        short8 w = *(const short8*)&W1t[t * 8];
        *(short8*)&lds[WD_E + (t >> 6) * WD_KS + (t & 63) * 8] = w;
    }
    __syncthreads();

    // ================= conv1: h1(16x16x64) =================
    {
        floatx4 acc[4][4];
#pragma unroll
        for (int mi = 0; mi < 4; ++mi) {
            float4 bb = *(const float4*)&B1[mi * 16 + q * 4];   // bias as C-init
            floatx4 ib = (floatx4){bb.x, bb.y, bb.z, bb.w};
#pragma unroll
            for (int n = 0; n < 4; ++n) acc[mi][n] = ib;
        }

        for (int tap = 0; tap < 9; ++tap) {
            int buf = tap & 1;
            short8 wnext;
            if (tap < 8) wnext = *(const short8*)&W1t[(tap + 1) * 2048 + t * 8];
            int dy = tap / 3, dx = tap - dy * 3;
            short8 Af[4], Bx[4];
#pragma unroll
            for (int mi = 0; mi < 4; ++mi)
                Af[mi] = *(const short8*)&lds[WD_E + buf * WD_BUF + q * WD_KS + (mi * 16 + m) * 8];
#pragma unroll
            for (int n = 0; n < 4; ++n) {
                int ptile = n * 4 + wave;
                Bx[n] = *(const short8*)&lds[X0_E + q * X0_KS + ((ptile + dy) * 18 + (m + dx)) * 8];
            }
#pragma unroll
            for (int mi = 0; mi < 4; ++mi)
#pragma unroll
                for (int n = 0; n < 4; ++n)
                    acc[mi][n] = __builtin_amdgcn_mfma_f32_16x16x32_bf16(Af[mi], Bx[n], acc[mi][n], 0, 0, 0);
            if (tap < 8)
                *(short8*)&lds[WD_E + (buf ^ 1) * WD_BUF + (t >> 6) * WD_KS + (t & 63) * 8] = wnext;
            __syncthreads();
        }
        // epilogue: relu (+mask on edge) -> h1, packed b64 stores
        if (!edge) {
#pragma unroll
            for (int mi = 0; mi < 4; ++mi) {
                int ks = mi * 2 + (q >> 1), lo = (q & 1) * 4;
#pragma unroll
                for (int n = 0; n < 4; ++n) {
                    int ptile = n * 4 + wave;
                    floatx4 a = acc[mi][n];
                    *(short4v*)&lds[H1_E + ks * H1_KS + (ptile * 16 + m) * 8 + lo] =
                        pack4(fmaxf(a[0], 0.f), fmaxf(a[1], 0.f), fmaxf(a[2], 0.f), fmaxf(a[3], 0.f));
                }
            }
        } else {
#pragma unroll
            for (int mi = 0; mi < 4; ++mi) {
                int ks = mi * 2 + (q >> 1), lo = (q & 1) * 4;
#pragma unroll
                for (int n = 0; n < 4; ++n) {
                    int ptile = n * 4 + wave;
                    int gy = ty0 - 2 + ptile, gx = tx0 - 2 + m;
                    bool ok = ((uint_t)gy < 512u) && ((uint_t)gx < 512u);
                    floatx4 a = acc[mi][n];
                    float v0 = ok ? fmaxf(a[0], 0.f) : 0.f;
                    float v1 = ok ? fmaxf(a[1], 0.f) : 0.f;
                    float v2 = ok ? fmaxf(a[2], 0.f) : 0.f;
                    float v3 = ok ? fmaxf(a[3], 0.f) : 0.f;
                    *(short4v*)&lds[H1_E + ks * H1_KS + (ptile * 16 + m) * 8 + lo] = pack4(v0, v1, v2, v3);
                }
            }
        }
    }
    __syncthreads();
    // stage W2 tap 0
    {
#pragma unroll
        for (int it = 0; it < 2; ++it) {
            int idx = t + it * 256;
            short8 w = *(const short8*)&W2t[idx * 8];
            *(short8*)&lds[WD_E + (idx >> 6) * WD_KS + (idx & 63) * 8] = w;
        }
    }
    __syncthreads();

    // ================= conv2: h2(14x14x64) =================
    {
        floatx4 acc[4][4];
#pragma unroll
        for (int mi = 0; mi < 4; ++mi) {
            float4 bb = *(const float4*)&B2[mi * 16 + q * 4];
            floatx4 ib = (floatx4){bb.x, bb.y, bb.z, bb.w};
#pragma unroll
            for (int n = 0; n < 4; ++n) acc[mi][n] = ib;
        }
        int hb2[4];
#pragma unroll
        for (int n = 0; n < 4; ++n) {
            int p0 = (n * 4 + wave) * 16 + m;
            int py = p0 / 14, px = p0 - py * 14;
            hb2[n] = py * 16 + px;
        }

        for (int tap = 0; tap < 9; ++tap) {
            int buf = tap & 1;
            short8 wn0, wn1;
            if (tap < 8) {
                wn0 = *(const short8*)&W2t[(tap + 1) * 4096 + t * 8];
                wn1 = *(const short8*)&W2t[(tap + 1) * 4096 + (t + 256) * 8];
            }
            int dy = tap / 3, dx = tap - dy * 3;
#pragma unroll
            for (int kh = 0; kh < 2; ++kh) {
                short8 Af[4], Bx[4];
#pragma unroll
                for (int mi = 0; mi < 4; ++mi)
                    Af[mi] = *(const short8*)&lds[WD_E + buf * WD_BUF + (kh * 4 + q) * WD_KS + (mi * 16 + m) * 8];
#pragma unroll
                for (int n = 0; n < 4; ++n)
                    Bx[n] = *(const short8*)&lds[H1_E + (kh * 4 + q) * H1_KS + (hb2[n] + dy * 16 + dx) * 8];
#pragma unroll
                for (int mi = 0; mi < 4; ++mi)
#pragma unroll
                    for (int n = 0; n < 4; ++n) {
                        int ptile = n * 4 + wave;
                        if (ptile < 13)
                            acc[mi][n] = __builtin_amdgcn_mfma_f32_16x16x32_bf16(Af[mi], Bx[n], acc[mi][n], 0, 0, 0);
                    }
            }
            if (tap < 8) {
                int nb = buf ^ 1;
                *(short8*)&lds[WD_E + nb * WD_BUF + (t >> 6) * WD_KS + (t & 63) * 8] = wn0;
                *(short8*)&lds[WD_E + nb * WD_BUF + ((t + 256) >> 6) * WD_KS + (t & 63) * 8] = wn1;
            }
            __syncthreads();
        }
        // epilogue: relu (+mask on edge) -> h2 [196][72], packed b64 stores
#pragma unroll
        for (int n = 0; n < 4; ++n) {
            int ptile = n * 4 + wave;
            if (ptile >= 13) continue;
            int p = ptile * 16 + m;
            bool pok = p < 196;
            bool ok = pok;
            if (edge) {
                int py = p / 14, px = p - py * 14;
                int gy = ty0 - 1 + py, gx = tx0 - 1 + px;
                ok = pok && ((uint_t)gy < 512u) && ((uint_t)gx < 512u);
            }
#pragma unroll
            for (int mi = 0; mi < 4; ++mi) {
                floatx4 a = acc[mi][n];
                float v0 = ok ? fmaxf(a[0], 0.f) : 0.f;
                float v1 = ok ? fmaxf(a[1], 0.f) : 0.f;
                float v2 = ok ? fmaxf(a[2], 0.f) : 0.f;
                float v3 = ok ? fmaxf(a[3], 0.f) : 0.f;
                if (pok)
                    *(short4v*)&lds[H2_E + p * 72 + mi * 16 + q * 4] = pack4(v0, v1, v2, v3);
            }
        }
    }
    // ---- W3A zero-fill (disjoint from h2 region) ----
    {
        short8 zz = {0, 0, 0, 0, 0, 0, 0, 0};
        for (int i = t; i < 1152; i += 256)
            *(short8*)&lds[W3A_E + i * 8] = zz;
    }
    __syncthreads();
    // ---- W3A value fill: rows ch<NCH of [18 k2][4 q][16 ch][8] ----
    const int cls = clsp[b];
    for (int i = t; i < 576 * NCH; i += 256) {
        int j = i & 7, rest = i >> 3;
        int ch, rest2;
        if (NCH == 2) { ch = rest & 1; rest2 = rest >> 1; }
        else          { ch = 0;        rest2 = rest; }
        int qq = rest2 & 3, t2 = rest2 >> 2;
        int tap = t2 >> 1, kh = t2 & 1;
        int ci = kh * 32 + qq * 8 + j;
        lds[W3A_E + t2 * 512 + qq * 128 + ch * 8 + j] =
            f2bf(W3[(size_t)(tap * 64 + ci) * C3TOT + cls * NCH + ch]);
    }
    __syncthreads();

    // ================= conv3 via MFMA: rows=out-ch, cols=pixels ============
    {
        floatx4 acc3[9];
#pragma unroll
        for (int n = 0; n < 9; ++n) acc3[n] = (floatx4){0.f, 0.f, 0.f, 0.f};
        int hb3[9];
#pragma unroll
        for (int n = 0; n < 9; ++n) {
            int p = n * 16 + m;
            int py = p / 12, px = p - py * 12;
            hb3[n] = py * 14 + px;
        }
        for (int t2 = wave; t2 < 18; t2 += 4) {
            int tap = t2 >> 1, kh = t2 & 1;
            int dy = tap / 3, dx = tap - dy * 3;
            short8 Aw = *(const short8*)&lds[W3A_E + t2 * 512 + q * 128 + m * 8];
#pragma unroll
            for (int n = 0; n < 9; ++n) {
                short8 Bh = *(const short8*)&lds[H2_E + (hb3[n] + dy * 14 + dx) * 72 + kh * 32 + q * 8];
                acc3[n] = __builtin_amdgcn_mfma_f32_16x16x32_bf16(Aw, Bh, acc3[n], 0, 0, 0);
            }
        }
        float* sf = ldsf + SF_F;
        if (q == 0) {
#pragma unroll
            for (int n = 0; n < 9; ++n) {
                float2 v = {acc3[n][0], acc3[n][1]};
                *(float2*)&sf[wave * 288 + n * 32 + m * 2] = v;
            }
        }
    }
    __syncthreads();
    if (t < 144) {
        float* sf = ldsf + SF_F;
        int p = t;
        int base = (p >> 4) * 32 + (p & 15) * 2;
        float a0 = sf[base] + sf[288 + base] + sf[576 + base] + sf[864 + base];
        int py = p / 12, px = p - py * 12;
        int gy = ty0 + py, gx = tx0 + px;
        if (gy < 512 && gx < 512) {
            size_t ob = (((size_t)b * 512 + gy) * 512 + gx) * NCH;
            outp[ob] = a0 + B3[cls * NCH + 0];
            if (NCH == 2) {
                float a1 = sf[base + 1] + sf[288 + base + 1] + sf[576 + base + 1] + sf[864 + base + 1];
                outp[ob + 1] = a1 + B3[cls * NCH + 1];
            }
        }
    }
}

extern "C" void kernel_launch(void* const* d_in, const int* in_sizes, int n_in,
                              void* d_out, int out_size, void* d_ws, size_t ws_size,
                              hipStream_t stream) {
    const float* x0  = (const float*)d_in[0];
    const float* f4  = (const float*)d_in[1];
    const float* Wo1 = (const float*)d_in[2];  const float* bo1 = (const float*)d_in[3];
    const float* Wo2 = (const float*)d_in[4];  const float* bo2 = (const float*)d_in[5];
    const float* Wo3 = (const float*)d_in[6];  const float* bo3 = (const float*)d_in[7];
    const float* Ww1 = (const float*)d_in[8];  const float* bw1 = (const float*)d_in[9];
    const float* Ww2 = (const float*)d_in[10]; const float* bw2 = (const float*)d_in[11];
    const float* Ww3 = (const float*)d_in[12]; const float* bw3 = (const float*)d_in[13];
    const float* Wc1 = (const float*)d_in[14]; const float* bc1 = (const float*)d_in[15];
    const float* Wc2 = (const float*)d_in[16]; const float* bc2 = (const float*)d_in[17];
    const float* Wc3 = (const float*)d_in[18]; const float* bc3 = (const float*)d_in[19];

    float* out = (float*)d_out;
    float* offsets_out = out;                      // (4,512,512,2)
    float* weights_out = out + 2097152;            // (4,512,512,1)
    float* pred_out    = out + 3145728;            // (4,3)
    int* cls_ws = (int*)d_ws;
    ushort_t* wt = (ushort_t*)((char*)d_ws + 16);  // tiled bf16 weights (216 KB)
    const ushort_t* W1o_t = wt;
    const ushort_t* W2o_t = wt + 18432;
    const ushort_t* W1w_t = wt + 55296;
    const ushort_t* W2w_t = wt + 73728;
    float* gap_part = (float*)((char*)d_ws + 221440);   // 4x8x256 floats (32 KB)

    prep_all<<<464, 256, 0, stream>>>(Wo1, Wo2, Ww1, Ww2, wt, f4, gap_part);
    cls_finish<<<4, 256, 0, stream>>>(gap_part, Wc1, bc1, Wc2, bc2, Wc3, bc3, pred_out, cls_ws);

    dim3 grid(43 * 43, 4, 2);
    fused_branch<<<grid, 256, 0, stream>>>(x0,
                                           W1o_t, W2o_t, W1w_t, W2w_t,
                                           bo1, bo2, bw1, bw2,
                                           Wo3, bo3, Ww3, bw3,
                                           cls_ws, offsets_out, weights_out);
}

// Round 7
// 613.587 us; speedup vs baseline: 9.2566x; 1.2527x over previous
//
#include <hip/hip_runtime.h>
#include <hip/hip_bf16.h>
#include <math.h>

typedef __attribute__((ext_vector_type(8))) short short8;
typedef __attribute__((ext_vector_type(4))) short short4v;
typedef __attribute__((ext_vector_type(4))) float floatx4;
typedef unsigned short ushort_t;
typedef unsigned int uint_t;

__device__ __forceinline__ ushort_t f2bf(float x) {   // RNE f32 -> bf16
    uint_t u = __float_as_uint(x);
    uint_t r = (u + 0x7fffu + ((u >> 16) & 1u)) >> 16;
    return (ushort_t)r;
}
// HW-packed RNE conversion: 2 floats -> packed bf16x2 (v_cvt_pk_bf16_f32)
__device__ __forceinline__ short4v pack4(float a, float b, float c, float d) {
    union { __hip_bfloat162 h; uint_t u; } lo, hi;
    lo.h = __float22bfloat162_rn(make_float2(a, b));
    hi.h = __float22bfloat162_rn(make_float2(c, d));
    short4v r;
    r[0] = (short)(lo.u & 0xffffu); r[1] = (short)(lo.u >> 16);
    r[2] = (short)(hi.u & 0xffffu); r[3] = (short)(hi.u >> 16);
    return r;
}
__device__ __forceinline__ short8 pack8(float4 v0, float4 v1) {
    short4v lo = pack4(v0.x, v0.y, v0.z, v0.w);
    short4v hi = pack4(v1.x, v1.y, v1.z, v1.w);
    short8 pk;
    pk[0] = lo[0]; pk[1] = lo[1]; pk[2] = lo[2]; pk[3] = lo[3];
    pk[4] = hi[0]; pk[5] = hi[1]; pk[6] = hi[2]; pk[7] = hi[3];
    return pk;
}

// ---------------- prep: weight tiling (W1/W2/W3) + partial GAP -------------
// blocks [0,432): W1/W2 bf16 MFMA tiles [tap][ci/8][64 co][8 ci]
// blocks [432,648): W3 tiles [branch][cls][18 t2][4 q][16 ch][8 j] (ch>=NCH -> 0)
// blocks [648,680): GAP partials
__global__ void prep_all(const float* __restrict__ W1a, const float* __restrict__ W2a,
                         const float* __restrict__ W1b, const float* __restrict__ W2b,
                         const float* __restrict__ W3a, const float* __restrict__ W3b,
                         ushort_t* __restrict__ wt, ushort_t* __restrict__ w3t,
                         const float* __restrict__ f4, float* __restrict__ part) {
    __shared__ float4 red[256];
    int bi = blockIdx.x, t = threadIdx.x;
    if (bi < 432) {
        int i = bi * 256 + t;
        const float* W; int off; int C;
        if (i < 18432)      { W = W1a; off = i;         C = 32; }
        else if (i < 55296) { W = W2a; off = i - 18432; C = 64; }
        else if (i < 73728) { W = W1b; off = i - 55296; C = 32; }
        else                { W = W2b; off = i - 73728; C = 64; }
        int pt = C * 64;
        int tap = off / pt, rem = off - tap * pt;
        int k4 = rem >> 9, rem2 = rem & 511;
        int co = rem2 >> 3, j = rem2 & 7;
        int ci = k4 * 8 + j;
        wt[i] = f2bf(W[(size_t)(tap * C + ci) * 64 + co]);
    } else if (bi < 648) {
        int i = (bi - 432) * 256 + t;          // [0, 55296)
        int branch = i / 27648; int r = i - branch * 27648;
        int cls = r / 9216; int r2 = r - cls * 9216;
        int t2 = r2 >> 9; int r3 = r2 & 511;
        int qq = r3 >> 7; int r4 = r3 & 127;
        int ch = r4 >> 3; int j = r4 & 7;
        int tap = t2 >> 1, kh = t2 & 1;
        int ci = kh * 32 + qq * 8 + j;
        int NCH = branch ? 1 : 2, C3 = branch ? 3 : 6;
        const float* W3 = branch ? W3b : W3a;
        ushort_t v = 0;
        if (ch < NCH) v = f2bf(W3[(size_t)(tap * 64 + ci) * C3 + cls * NCH + ch]);
        w3t[i] = v;
    } else {
        int g = bi - 648;
        int c = g & 7, b = g >> 3;
        int ci4 = t & 63, po = t >> 6;
        const float* f = f4 + ((size_t)b * 1024 + c * 128) * 256;
        float4 s = {0, 0, 0, 0};
        for (int i = 0; i < 32; ++i) {
            float4 v = *(const float4*)&f[(size_t)(i * 4 + po) * 256 + ci4 * 4];
            s.x += v.x; s.y += v.y; s.z += v.z; s.w += v.w;
        }
        red[t] = s;
        __syncthreads();
        if (t < 64) {
            float4 a = red[t], b2 = red[64 + t], c2 = red[128 + t], d2 = red[192 + t];
            float4 gg;
            gg.x = a.x + b2.x + c2.x + d2.x;
            gg.y = a.y + b2.y + c2.y + d2.y;
            gg.z = a.z + b2.z + c2.z + d2.z;
            gg.w = a.w + b2.w + c2.w + d2.w;
            *(float4*)&part[((b * 8 + c) << 8) + t * 4] = gg;
        }
    }
}

// ---------------- classifier finish: MLP + softmax + argmax ----------------
__global__ void cls_finish(const float* __restrict__ part,
                           const float* __restrict__ Wc1, const float* __restrict__ bc1,
                           const float* __restrict__ Wc2, const float* __restrict__ bc2,
                           const float* __restrict__ Wc3, const float* __restrict__ bc3,
                           float* __restrict__ pred_out, int* __restrict__ cls_out) {
    int b = blockIdx.x;
    int t = threadIdx.x;                       // 256 threads
    __shared__ float gap[256];
    __shared__ float z1[128];
    __shared__ float z2[128];
    __shared__ float lg[3];
    float s = 0.f;
    for (int c = 0; c < 8; ++c) s += part[((b * 8 + c) << 8) + t];
    gap[t] = s * (1.0f / 1024.0f);
    __syncthreads();
    if (t < 128) {
        float a = bc1[t];
        for (int i = 0; i < 256; ++i) a += gap[i] * Wc1[i * 128 + t];
        z1[t] = fmaxf(a, 0.f);
    }
    __syncthreads();
    if (t < 128) {
        float a = bc2[t];
        for (int i = 0; i < 128; ++i) a += z1[i] * Wc2[i * 128 + t];
        z2[t] = fmaxf(a, 0.f);
    }
    __syncthreads();
    if (t < 3) {
        float a = bc3[t];
        for (int i = 0; i < 128; ++i) a += z2[i] * Wc3[i * 3 + t];
        lg[t] = a;
    }
    __syncthreads();
    if (t == 0) {
        float m = fmaxf(lg[0], fmaxf(lg[1], lg[2]));
        float e0 = expf(lg[0] - m), e1 = expf(lg[1] - m), e2 = expf(lg[2] - m);
        float ssum = e0 + e1 + e2;
        pred_out[b * 3 + 0] = e0 / ssum;
        pred_out[b * 3 + 1] = e1 / ssum;
        pred_out[b * 3 + 2] = e2 / ssum;
        int idx = 0; float best = lg[0];
        if (lg[1] > best) { best = lg[1]; idx = 1; }
        if (lg[2] > best) { best = lg[2]; idx = 2; }
        cls_out[b] = idx;
    }
}

// ---------------- fused MFMA conv branch (both branches, grid.z) -----------
// A = weights DIRECT FROM GLOBAL (pre-tiled, L1/L2-resident); B = pixels in
// LDS. No per-tap barriers (x0/h1 read-only during tap loops): 5 barriers.
// LDS (ushort):
//   x0  [4 ks x 2592]           : [0, 10368)
//   h1  [8 ks x 2048]           : [10368, 26752)
//   h2  [196 px][72]            : [0, 14112)      (x0 + h1-head, post-conv2)
//   SF  float partials 1152     : floats [7200,8352) = ushort [14400,16704)
// Total 53504 B -> 3 blocks/CU.
#define X0_E 0
#define X0_KS 2592
#define H1_E 10368
#define H1_KS 2048
#define H2_E 0
#define SF_F 7200
#define LDS_E 26752

__global__ __launch_bounds__(256, 3)
void fused_branch(const float* __restrict__ x0,
                  const ushort_t* __restrict__ W1o_t, const ushort_t* __restrict__ W2o_t,
                  const ushort_t* __restrict__ W1w_t, const ushort_t* __restrict__ W2w_t,
                  const ushort_t* __restrict__ w3t,
                  const float* __restrict__ bo1, const float* __restrict__ bo2,
                  const float* __restrict__ bw1, const float* __restrict__ bw2,
                  const float* __restrict__ bo3, const float* __restrict__ bw3,
                  const int* __restrict__ clsp,
                  float* __restrict__ off_out, float* __restrict__ w_out) {
    __shared__ __align__(16) ushort_t lds[LDS_E];
    float* ldsf = (float*)lds;
    const int t = threadIdx.x;
    const int b = blockIdx.y;
    const int z = blockIdx.z;
    const ushort_t* W1t = z ? W1w_t : W1o_t;
    const ushort_t* W2t = z ? W2w_t : W2o_t;
    const ushort_t* W3T = w3t + z * 27648;
    const float* B1 = z ? bw1 : bo1;
    const float* B2 = z ? bw2 : bo2;
    const float* B3 = z ? bw3 : bo3;
    float* outp = z ? w_out : off_out;
    const int NCH = z ? 1 : 2;

    const int tileY = blockIdx.x / 43, tileX = blockIdx.x - tileY * 43;
    const int ty0 = tileY * 12, tx0 = tileX * 12;
    const bool edge = (tileY == 0) | (tileY == 42) | (tileX == 0) | (tileX == 42);
    const int lane = t & 63, wave = t >> 6;
    const int m = lane & 15, q = lane >> 4;
    const int cls = clsp[b];

    // ---- stage x0 (18x18x32 fp32 -> bf16 [4 ks][324 px][8]) ----
    if (!edge) {
        for (int idx = t; idx < 1296; idx += 256) {
            int pix = idx >> 2, qq = idx & 3;
            int py = pix / 18, px = pix - py * 18;
            const float* xp = x0 + (((size_t)b * 512 + (ty0 - 3 + py)) * 512 + (tx0 - 3 + px)) * 32 + qq * 8;
            *(short8*)&lds[X0_E + qq * X0_KS + pix * 8] =
                pack8(*(const float4*)xp, *(const float4*)(xp + 4));
        }
    } else {
        for (int idx = t; idx < 1296; idx += 256) {
            int pix = idx >> 2, qq = idx & 3;
            int py = pix / 18, px = pix - py * 18;
            int gy = ty0 - 3 + py, gx = tx0 - 3 + px;
            float4 v0 = {0, 0, 0, 0}, v1 = {0, 0, 0, 0};
            if ((uint_t)gy < 512u && (uint_t)gx < 512u) {
                const float* xp = x0 + (((size_t)b * 512 + gy) * 512 + gx) * 32 + qq * 8;
                v0 = *(const float4*)xp;
                v1 = *(const float4*)(xp + 4);
            }
            *(short8*)&lds[X0_E + qq * X0_KS + pix * 8] = pack8(v0, v1);
        }
    }
    __syncthreads();                                   // (1)

    // ================= conv1: h1(16x16x64), A from global =================
    {
        floatx4 acc[4][4];
#pragma unroll
        for (int mi = 0; mi < 4; ++mi) {
            float4 bb = *(const float4*)&B1[mi * 16 + q * 4];   // bias as C-init
            floatx4 ib = (floatx4){bb.x, bb.y, bb.z, bb.w};
#pragma unroll
            for (int n = 0; n < 4; ++n) acc[mi][n] = ib;
        }
        const int wsel = q * 512 + m * 8;
        short8 Anow[4];
#pragma unroll
        for (int mi = 0; mi < 4; ++mi)
            Anow[mi] = *(const short8*)&W1t[wsel + mi * 128];

        for (int tap = 0; tap < 9; ++tap) {
            int tn = tap < 8 ? tap + 1 : 8;
            short8 Anext[4];
#pragma unroll
            for (int mi = 0; mi < 4; ++mi)
                Anext[mi] = *(const short8*)&W1t[tn * 2048 + wsel + mi * 128];
            int dy = tap / 3, dx = tap - dy * 3;
            short8 Bx[4];
#pragma unroll
            for (int n = 0; n < 4; ++n) {
                int ptile = n * 4 + wave;
                Bx[n] = *(const short8*)&lds[X0_E + q * X0_KS + ((ptile + dy) * 18 + (m + dx)) * 8];
            }
#pragma unroll
            for (int mi = 0; mi < 4; ++mi)
#pragma unroll
                for (int n = 0; n < 4; ++n)
                    acc[mi][n] = __builtin_amdgcn_mfma_f32_16x16x32_bf16(Anow[mi], Bx[n], acc[mi][n], 0, 0, 0);
#pragma unroll
            for (int mi = 0; mi < 4; ++mi) Anow[mi] = Anext[mi];
        }
        // epilogue: relu (+mask on edge) -> h1, packed b64 stores
        if (!edge) {
#pragma unroll
            for (int mi = 0; mi < 4; ++mi) {
                int ks = mi * 2 + (q >> 1), lo = (q & 1) * 4;
#pragma unroll
                for (int n = 0; n < 4; ++n) {
                    int ptile = n * 4 + wave;
                    floatx4 a = acc[mi][n];
                    *(short4v*)&lds[H1_E + ks * H1_KS + (ptile * 16 + m) * 8 + lo] =
                        pack4(fmaxf(a[0], 0.f), fmaxf(a[1], 0.f), fmaxf(a[2], 0.f), fmaxf(a[3], 0.f));
                }
            }
        } else {
#pragma unroll
            for (int mi = 0; mi < 4; ++mi) {
                int ks = mi * 2 + (q >> 1), lo = (q & 1) * 4;
#pragma unroll
                for (int n = 0; n < 4; ++n) {
                    int ptile = n * 4 + wave;
                    int gy = ty0 - 2 + ptile, gx = tx0 - 2 + m;
                    bool ok = ((uint_t)gy < 512u) && ((uint_t)gx < 512u);
                    floatx4 a = acc[mi][n];
                    float v0 = ok ? fmaxf(a[0], 0.f) : 0.f;
                    float v1 = ok ? fmaxf(a[1], 0.f) : 0.f;
                    float v2 = ok ? fmaxf(a[2], 0.f) : 0.f;
                    float v3 = ok ? fmaxf(a[3], 0.f) : 0.f;
                    *(short4v*)&lds[H1_E + ks * H1_KS + (ptile * 16 + m) * 8 + lo] = pack4(v0, v1, v2, v3);
                }
            }
        }
    }
    __syncthreads();                                   // (2)

    // ================= conv2: h2(14x14x64), A from global =================
    {
        floatx4 acc[4][4];
#pragma unroll
        for (int mi = 0; mi < 4; ++mi) {
            float4 bb = *(const float4*)&B2[mi * 16 + q * 4];
            floatx4 ib = (floatx4){bb.x, bb.y, bb.z, bb.w};
#pragma unroll
            for (int n = 0; n < 4; ++n) acc[mi][n] = ib;
        }
        int hb2[4];
#pragma unroll
        for (int n = 0; n < 4; ++n) {
            int p0 = (n * 4 + wave) * 16 + m;
            int pv = p0 < 196 ? p0 : 195;              // clamp unused tiles in-range
            int py = pv / 14, px = pv - py * 14;
            hb2[n] = py * 16 + px;
        }
        const int wsel = q * 512 + m * 8;
        short8 Anow[4];
#pragma unroll
        for (int mi = 0; mi < 4; ++mi)
            Anow[mi] = *(const short8*)&W2t[wsel + mi * 128];

        for (int s = 0; s < 18; ++s) {
            int tap = s >> 1, kh = s & 1;
            int sn = s < 17 ? s + 1 : 17;
            short8 Anext[4];
#pragma unroll
            for (int mi = 0; mi < 4; ++mi)
                Anext[mi] = *(const short8*)&W2t[(sn >> 1) * 4096 + ((sn & 1) * 4) * 512 + wsel + mi * 128];
            int dy = tap / 3, dx = tap - dy * 3;
            short8 Bx[4];
#pragma unroll
            for (int n = 0; n < 4; ++n)
                Bx[n] = *(const short8*)&lds[H1_E + (kh * 4 + q) * H1_KS + (hb2[n] + dy * 16 + dx) * 8];
#pragma unroll
            for (int mi = 0; mi < 4; ++mi)
#pragma unroll
                for (int n = 0; n < 4; ++n) {
                    int ptile = n * 4 + wave;
                    if (ptile < 13)
                        acc[mi][n] = __builtin_amdgcn_mfma_f32_16x16x32_bf16(Anow[mi], Bx[n], acc[mi][n], 0, 0, 0);
                }
#pragma unroll
            for (int mi = 0; mi < 4; ++mi) Anow[mi] = Anext[mi];
        }
        __syncthreads();                               // (3) protect h1 reads
        // epilogue: relu (+mask on edge) -> h2 [196][72], packed b64 stores
#pragma unroll
        for (int n = 0; n < 4; ++n) {
            int ptile = n * 4 + wave;
            if (ptile >= 13) continue;
            int p = ptile * 16 + m;
            bool pok = p < 196;
            bool ok = pok;
            if (edge) {
                int py = p / 14, px = p - py * 14;
                int gy = ty0 - 1 + py, gx = tx0 - 1 + px;
                ok = pok && ((uint_t)gy < 512u) && ((uint_t)gx < 512u);
            }
#pragma unroll
            for (int mi = 0; mi < 4; ++mi) {
                floatx4 a = acc[mi][n];
                float v0 = ok ? fmaxf(a[0], 0.f) : 0.f;
                float v1 = ok ? fmaxf(a[1], 0.f) : 0.f;
                float v2 = ok ? fmaxf(a[2], 0.f) : 0.f;
                float v3 = ok ? fmaxf(a[3], 0.f) : 0.f;
                if (pok)
                    *(short4v*)&lds[H2_E + p * 72 + mi * 16 + q * 4] = pack4(v0, v1, v2, v3);
            }
        }
    }
    __syncthreads();                                   // (4)

    // ========== conv3 via MFMA: A (selected W3) from global ==========
    {
        floatx4 acc3[9];
#pragma unroll
        for (int n = 0; n < 9; ++n) acc3[n] = (floatx4){0.f, 0.f, 0.f, 0.f};
        int hb3[9];
#pragma unroll
        for (int n = 0; n < 9; ++n) {
            int p = n * 16 + m;
            int py = p / 12, px = p - py * 12;
            hb3[n] = py * 14 + px;
        }
        const ushort_t* W3c = W3T + cls * 9216;
        for (int t2 = wave; t2 < 18; t2 += 4) {
            int tap = t2 >> 1, kh = t2 & 1;
            int dy = tap / 3, dx = tap - dy * 3;
            short8 Aw = *(const short8*)&W3c[t2 * 512 + q * 128 + m * 8];
#pragma unroll
            for (int n = 0; n < 9; ++n) {
                short8 Bh = *(const short8*)&lds[H2_E + (hb3[n] + dy * 14 + dx) * 72 + kh * 32 + q * 8];
                acc3[n] = __builtin_amdgcn_mfma_f32_16x16x32_bf16(Aw, Bh, acc3[n], 0, 0, 0);
            }
        }
        float* sf = ldsf + SF_F;
        if (q == 0) {
#pragma unroll
            for (int n = 0; n < 9; ++n) {
                float2 v = {acc3[n][0], acc3[n][1]};
                *(float2*)&sf[wave * 288 + n * 32 + m * 2] = v;
            }
        }
    }
    __syncthreads();                                   // (5)
    if (t < 144) {
        float* sf = ldsf + SF_F;
        int p = t;
        int base = (p >> 4) * 32 + (p & 15) * 2;
        float a0 = sf[base] + sf[288 + base] + sf[576 + base] + sf[864 + base];
        int py = p / 12, px = p - py * 12;
        int gy = ty0 + py, gx = tx0 + px;
        if (gy < 512 && gx < 512) {
            size_t ob = (((size_t)b * 512 + gy) * 512 + gx) * NCH;
            outp[ob] = a0 + B3[cls * NCH + 0];
            if (NCH == 2) {
                float a1 = sf[base + 1] + sf[288 + base + 1] + sf[576 + base + 1] + sf[864 + base + 1];
                outp[ob + 1] = a1 + B3[cls * NCH + 1];
            }
        }
    }
}

extern "C" void kernel_launch(void* const* d_in, const int* in_sizes, int n_in,
                              void* d_out, int out_size, void* d_ws, size_t ws_size,
                              hipStream_t stream) {
    const float* x0  = (const float*)d_in[0];
    const float* f4  = (const float*)d_in[1];
    const float* Wo1 = (const float*)d_in[2];  const float* bo1 = (const float*)d_in[3];
    const float* Wo2 = (const float*)d_in[4];  const float* bo2 = (const float*)d_in[5];
    const float* Wo3 = (const float*)d_in[6];  const float* bo3 = (const float*)d_in[7];
    const float* Ww1 = (const float*)d_in[8];  const float* bw1 = (const float*)d_in[9];
    const float* Ww2 = (const float*)d_in[10]; const float* bw2 = (const float*)d_in[11];
    const float* Ww3 = (const float*)d_in[12]; const float* bw3 = (const float*)d_in[13];
    const float* Wc1 = (const float*)d_in[14]; const float* bc1 = (const float*)d_in[15];
    const float* Wc2 = (const float*)d_in[16]; const float* bc2 = (const float*)d_in[17];
    const float* Wc3 = (const float*)d_in[18]; const float* bc3 = (const float*)d_in[19];

    float* out = (float*)d_out;
    float* offsets_out = out;                      // (4,512,512,2)
    float* weights_out = out + 2097152;            // (4,512,512,1)
    float* pred_out    = out + 3145728;            // (4,3)

    int* cls_ws = (int*)d_ws;                              // 16 B
    ushort_t* wt  = (ushort_t*)((char*)d_ws + 16);         // 110592 ushorts
    ushort_t* w3t = (ushort_t*)((char*)d_ws + 221200);     // 2x27648 ushorts
    float* gap_part = (float*)((char*)d_ws + 331792);      // 4x8x256 floats

    const ushort_t* W1o_t = wt;
    const ushort_t* W2o_t = wt + 18432;
    const ushort_t* W1w_t = wt + 55296;
    const ushort_t* W2w_t = wt + 73728;

    prep_all<<<680, 256, 0, stream>>>(Wo1, Wo2, Ww1, Ww2, Wo3, Ww3, wt, w3t, f4, gap_part);
    cls_finish<<<4, 256, 0, stream>>>(gap_part, Wc1, bc1, Wc2, bc2, Wc3, bc3, pred_out, cls_ws);

    dim3 grid(43 * 43, 4, 2);
    fused_branch<<<grid, 256, 0, stream>>>(x0,
                                           W1o_t, W2o_t, W1w_t, W2w_t, w3t,
                                           bo1, bo2, bw1, bw2,
                                           bo3, bw3,
                                           cls_ws, offsets_out, weights_out);
}